// Round 1
// baseline (221.986 us; speedup 1.0000x reference)
//
#include <hip/hip_runtime.h>
#include <math.h>

#define N_CELLS 65536
#define HIDDEN  128
#define IN_DIM  64
#define MAX_DEG 6

#define NW    4096                 // total waves in main kernel
#define CHUNK (N_CELLS / NW)       // 16 nodes per wave

// ---- ws byte offsets (total ~4.3 MiB) ----
#define WS_PP   0                                  // 128 f32
#define WS_FLAG 512                                // 1 int
#define WS_STR  1024                               // 65536 f32
#define WS_PRE  (1024 + N_CELLS*4)                 // NW*128 f32
#define WS_PIM  (WS_PRE + NW*HIDDEN*4)             // NW*128 f32
#define WS_SA   (WS_PIM + NW*HIDDEN*4)             // NW f32
#define WS_SA2  (WS_SA + NW*4)                     // NW f32

// P0: sig = W_in @ x + b_in ; pp = sig/(max|sig|+1e-8)*0.1*pi ; mask-layout detect
__global__ void k_prep(const float* __restrict__ x,
                       const float* __restrict__ W_in,
                       const float* __restrict__ b_in,
                       const unsigned char* __restrict__ maskb,
                       float* __restrict__ pp, int* __restrict__ flag)
{
    __shared__ float sig[HIDDEN];
    __shared__ float red[HIDDEN];
    __shared__ int fl[256];
    const int tid = threadIdx.x;
    if (tid < HIDDEN) {
        float acc = b_in[tid];
        #pragma unroll 8
        for (int d = 0; d < IN_DIM; ++d) acc = fmaf(W_in[tid*IN_DIM + d], x[d], acc);
        sig[tid] = acc;
        red[tid] = fabsf(acc);
    }
    // layout probe: bytes at offset 4k+1 are all 0 iff elements are 4-byte
    int v = 0;
    #pragma unroll
    for (int r = 0; r < 4; ++r) v |= (int)maskb[(tid + 256*r)*4 + 1];
    fl[tid] = v;
    __syncthreads();
    for (int s = 64; s > 0; s >>= 1) {
        if (tid < s) red[tid] = fmaxf(red[tid], red[tid + s]);
        __syncthreads();
    }
    for (int s = 128; s > 0; s >>= 1) {
        if (tid < s) fl[tid] |= fl[tid + s];
        __syncthreads();
    }
    if (tid < HIDDEN) pp[tid] = sig[tid] / (red[0] + 1e-8f) * 0.314159265f;
    if (tid == 0) *flag = (fl[0] != 0) ? 1 : 0;   // 1 => 1-byte bool layout
}

// P1: strength[i] = sum_h amp[i,h]  (|states| == amp exactly in math)
__global__ void k_strength(const float* __restrict__ amp, float* __restrict__ strength)
{
    const int w    = (blockIdx.x * blockDim.x + threadIdx.x) >> 6; // node
    const int lane = threadIdx.x & 63;
    const float2 v = ((const float2*)(amp + (size_t)w * HIDDEN))[lane];
    float s = v.x + v.y;
    #pragma unroll
    for (int off = 32; off > 0; off >>= 1) s += __shfl_xor(s, off);
    if (lane == 0) strength[w] = s;
}

// MAIN: one wave per node, CHUNK nodes per wave; lane owns h = 2*lane, 2*lane+1
__global__ __launch_bounds__(256) void k_main(
    const float* __restrict__ amp, const float* __restrict__ phase,
    const float* __restrict__ vel, const int* __restrict__ nbr_idx,
    const float* __restrict__ nbr_sign, const void* __restrict__ nbr_mask,
    const int* __restrict__ step, const float* __restrict__ pp,
    const int* __restrict__ flagp, const float* __restrict__ strength,
    float* __restrict__ p_re, float* __restrict__ p_im,
    float* __restrict__ p_sa, float* __restrict__ p_sa2)
{
    const int w    = blockIdx.x * (blockDim.x >> 6) + (threadIdx.x >> 6);
    const int lane = threadIdx.x & 63;
    const int flag = *flagp;
    const float t  = 0.1f * (float)step[0];
    const float pp0 = pp[2*lane], pp1 = pp[2*lane + 1];
    const unsigned char* mb = (const unsigned char*)nbr_mask;
    const int*           mi = (const int*)nbr_mask;

    float accre0=0.f, accre1=0.f, accim0=0.f, accim1=0.f, accsa=0.f, accsa2=0.f;
    const int base = w * CHUNK;

    for (int c = 0; c < CHUNK; ++c) {
        const int i = base + c;
        // ---- uniform per-node prep: mask bits, degree, argmax neighbor ----
        int deg = 0, bslot = -1, mkbits = 0;
        float bstr = -3.0e38f;
        int jidx[MAX_DEG]; float sgn[MAX_DEG];
        #pragma unroll
        for (int k = 0; k < MAX_DEG; ++k) {
            const int e = i*MAX_DEG + k;
            const int m = flag ? (int)mb[e] : (mi[e] != 0);
            jidx[k] = nbr_idx[e];
            sgn[k]  = nbr_sign[e];
            if (m) {
                mkbits |= (1 << k);
                ++deg;
                const float st = strength[jidx[k]];
                if (st > bstr) { bstr = st; bslot = k; }   // strict > keeps first max
            }
        }
        // ---- own state ----
        const float2 av = ((const float2*)(amp   + (size_t)i*HIDDEN))[lane];
        const float2 pv = ((const float2*)(phase + (size_t)i*HIDDEN))[lane];
        const float2 vv = ((const float2*)(vel   + (size_t)i*HIDDEN))[lane];
        float s0,c0,s1,c1;
        sincosf(fmaf(0.1f, vv.x, pv.x), &s0, &c0);
        sincosf(fmaf(0.1f, vv.y, pv.y), &s1, &c1);
        const float sr0 = av.x*c0, si0 = av.x*s0, sr1 = av.y*c1, si1 = av.y*s1;

        // ---- neighbor interference ----
        float ir0=0.f, ii0=0.f, ir1=0.f, ii1=0.f;
        float ab0=0.f, cb0=1.f, sb0=0.f, ab1=0.f, cb1=1.f, sb1=0.f;
        #pragma unroll
        for (int k = 0; k < MAX_DEG; ++k) {
            if (!(mkbits & (1 << k))) continue;
            const size_t jo = (size_t)jidx[k]*HIDDEN;
            const float2 aj = ((const float2*)(amp   + jo))[lane];
            const float2 pj = ((const float2*)(phase + jo))[lane];
            const float2 vj = ((const float2*)(vel   + jo))[lane];
            float sj0,cj0,sj1,cj1;
            sincosf(fmaf(0.1f, vj.x, pj.x), &sj0, &cj0);
            sincosf(fmaf(0.1f, vj.y, pj.y), &sj1, &cj1);
            const float cpl0 = (c0*cj0 + s0*sj0) * sgn[k];  // cos(a_i - a_j)*sign
            const float cpl1 = (c1*cj1 + s1*sj1) * sgn[k];
            ir0 += cpl0*aj.x*cj0;  ii0 += cpl0*aj.x*sj0;
            ir1 += cpl1*aj.y*cj1;  ii1 += cpl1*aj.y*sj1;
            if (k == bslot) { ab0=aj.x; cb0=cj0; sb0=sj0; ab1=aj.y; cb1=cj1; sb1=sj1; }
        }
        float nr0, ni0, nr1, ni1;
        if (deg > 0) {
            const float invd = 1.0f / (float)deg;
            nr0 = 0.7f*sr0 + (0.3f*(0.1f*ir0))*invd;
            ni0 = 0.7f*si0 + (0.3f*(0.1f*ii0))*invd;
            nr1 = 0.7f*sr1 + (0.3f*(0.1f*ir1))*invd;
            ni1 = 0.7f*si1 + (0.3f*(0.1f*ii1))*invd;
        } else { nr0=sr0; ni0=si0; nr1=sr1; ni1=si1; }

        // ---- morphism toward strongest neighbor ----
        if (deg >= 2) {
            const float g0 = 0.02f * ab0 / sqrtf(nr0*nr0 + ni0*ni0);
            const float mr0 = g0*(nr0*cb0 + ni0*sb0);
            const float mi0 = g0*(ni0*cb0 - nr0*sb0);
            const float g1 = 0.02f * ab1 / sqrtf(nr1*nr1 + ni1*ni1);
            const float mr1 = g1*(nr1*cb1 + ni1*sb1);
            const float mi1 = g1*(ni1*cb1 - nr1*sb1);
            nr0 += mr0; ni0 += mi0; nr1 += mr1; ni1 += mi1;
        }

        // ---- traveling wave ----
        const float wf = 1.0f + 0.02f*sinf(fmaf((float)i, 9.58737992e-5f, t)); // 2pi/65536
        nr0 *= wf; ni0 *= wf; nr1 *= wf; ni1 *= wf;

        // ---- input-driven phase rotation for i < 32 ----
        if (i < 32) {
            const float fac = 0.1f / fmaf(0.1f, (float)i, 1.0f);
            float sp0,cp0,sp1,cp1;
            sincosf(pp0*fac, &sp0, &cp0);
            sincosf(pp1*fac, &sp1, &cp1);
            float tr = nr0*cp0 - ni0*sp0;  ni0 = ni0*cp0 + nr0*sp0;  nr0 = tr;
            tr       = nr1*cp1 - ni1*sp1;  ni1 = ni1*cp1 + nr1*sp1;  nr1 = tr;
        }

        // ---- amplitude renorm: cs = new/(rowmax|new|+1e-8) ----
        const float m0 = sqrtf(nr0*nr0 + ni0*ni0);
        const float m1 = sqrtf(nr1*nr1 + ni1*ni1);
        float lm = fmaxf(m0, m1);
        #pragma unroll
        for (int off = 32; off > 0; off >>= 1) lm = fmaxf(lm, __shfl_xor(lm, off));
        const float sc = 1.0f / (lm + 1e-8f);
        accre0 += nr0*sc; accim0 += ni0*sc;
        accre1 += nr1*sc; accim1 += ni1*sc;
        const float A0 = m0*sc, A1 = m1*sc;
        accsa  += A0 + A1;
        accsa2 += A0*A0 + A1*A1;
    }

    ((float2*)(p_re + (size_t)w*HIDDEN))[lane] = make_float2(accre0, accre1);
    ((float2*)(p_im + (size_t)w*HIDDEN))[lane] = make_float2(accim0, accim1);
    float ss = accsa, ss2 = accsa2;
    #pragma unroll
    for (int off = 32; off > 0; off >>= 1) { ss += __shfl_xor(ss, off); ss2 += __shfl_xor(ss2, off); }
    if (lane == 0) { p_sa[w] = ss; p_sa2[w] = ss2; }
}

// FINAL: deterministic reductions + readout
__global__ void k_final(const float* __restrict__ p_re, const float* __restrict__ p_im,
                        const float* __restrict__ p_sa, const float* __restrict__ p_sa2,
                        const float* __restrict__ W_dec, const float* __restrict__ b_dec,
                        float* __restrict__ out)
{
    __shared__ float  mean[2*HIDDEN];
    __shared__ double dred[256];
    __shared__ double tots[2];
    const int tid = threadIdx.x;
    {
        const float* src = (tid < HIDDEN) ? p_re : p_im;
        const int h = tid & (HIDDEN - 1);
        double s = 0.0;
        for (int w = 0; w < NW; ++w) s += (double)src[(size_t)w*HIDDEN + h];
        mean[tid] = (float)(s / (double)N_CELLS);
    }
    double sa = 0.0, sa2 = 0.0;
    #pragma unroll
    for (int r = 0; r < NW/256; ++r) {
        sa  += (double)p_sa [tid + 256*r];
        sa2 += (double)p_sa2[tid + 256*r];
    }
    dred[tid] = sa;
    __syncthreads();
    for (int s = 128; s > 0; s >>= 1) { if (tid < s) dred[tid] += dred[tid + s]; __syncthreads(); }
    if (tid == 0) tots[0] = dred[0];
    __syncthreads();
    dred[tid] = sa2;
    __syncthreads();
    for (int s = 128; s > 0; s >>= 1) { if (tid < s) dred[tid] += dred[tid + s]; __syncthreads(); }
    if (tid == 0) tots[1] = dred[0];
    __syncthreads();

    if (tid < IN_DIM) {
        float acc = b_dec[tid];
        #pragma unroll 8
        for (int c = 0; c < 2*HIDDEN; ++c) acc = fmaf(mean[c], W_dec[tid*2*HIDDEN + c], acc);
        out[tid] = acc;
    }
    if (tid == 0) {
        const double M = (double)N_CELLS * (double)HIDDEN;
        const double var = (tots[1] - tots[0]*tots[0]/M) / (M - 1.0);
        out[IN_DIM] = (float)var;
    }
}

extern "C" void kernel_launch(void* const* d_in, const int* in_sizes, int n_in,
                              void* d_out, int out_size, void* d_ws, size_t ws_size,
                              hipStream_t stream)
{
    const float* x       = (const float*)d_in[0];
    const float* amp     = (const float*)d_in[1];
    const float* phase   = (const float*)d_in[2];
    const float* vel     = (const float*)d_in[3];
    const int*   nbr_idx = (const int*)d_in[4];
    const float* nbr_sgn = (const float*)d_in[5];
    const void*  nbr_msk = d_in[6];
    const float* W_in    = (const float*)d_in[7];
    const float* b_in    = (const float*)d_in[8];
    const float* W_dec   = (const float*)d_in[9];
    const float* b_dec   = (const float*)d_in[10];
    const int*   step    = (const int*)d_in[11];

    char* wsb = (char*)d_ws;
    float* pp    = (float*)(wsb + WS_PP);
    int*   flag  = (int*)  (wsb + WS_FLAG);
    float* strg  = (float*)(wsb + WS_STR);
    float* p_re  = (float*)(wsb + WS_PRE);
    float* p_im  = (float*)(wsb + WS_PIM);
    float* p_sa  = (float*)(wsb + WS_SA);
    float* p_sa2 = (float*)(wsb + WS_SA2);
    float* out   = (float*)d_out;

    k_prep<<<1, 256, 0, stream>>>(x, W_in, b_in, (const unsigned char*)nbr_msk, pp, flag);
    k_strength<<<N_CELLS/4, 256, 0, stream>>>(amp, strg);
    k_main<<<NW/4, 256, 0, stream>>>(amp, phase, vel, nbr_idx, nbr_sgn, nbr_msk,
                                     step, pp, flag, strg, p_re, p_im, p_sa, p_sa2);
    k_final<<<1, 256, 0, stream>>>(p_re, p_im, p_sa, p_sa2, W_dec, b_dec, out);
}

// Round 2
// 115.088 us; speedup vs baseline: 1.9288x; 1.9288x over previous
//
#include <hip/hip_runtime.h>
#include <math.h>

#define N_CELLS 65536
#define HIDDEN  128
#define IN_DIM  64
#define MAX_DEG 6

#define WPB    4                    // waves per block
#define NBLK   2048                 // main-kernel blocks (8/CU -> full occupancy)
#define NWAVES (NBLK*WPB)           // 8192
#define CHUNK  (N_CELLS/NWAVES)     // 8 nodes per wave

// ---- ws byte offsets (total ~2.3 MiB) ----
#define WS_PP    0                                  // 128 f32
#define WS_FLAG  512                                // 1 int
#define WS_STR   1024                               // 65536 f32
#define WS_P     (1024 + N_CELLS*4)                 // 256 x NBLK f32 (rows 0..127 re, 128..255 im)
#define WS_SA    (WS_P + 256*NBLK*4)                // NBLK f32
#define WS_SA2   (WS_SA + NBLK*4)                   // NBLK f32
#define WS_MEAN  (WS_SA2 + NBLK*4)                  // 256 f32

#define INV2PI 0.15915494309189535f

__device__ __forceinline__ void fsincos(float x, float& s, float& c) {
    const float r = x * INV2PI;                     // revolutions for v_sin/v_cos
    s = __builtin_amdgcn_sinf(r);
    c = __builtin_amdgcn_cosf(r);
}

// P0: sig = W_in @ x + b_in ; pp = sig/(max|sig|+1e-8)*0.1*pi ; mask-layout detect
__global__ void k_prep(const float* __restrict__ x,
                       const float* __restrict__ W_in,
                       const float* __restrict__ b_in,
                       const unsigned char* __restrict__ maskb,
                       float* __restrict__ pp, int* __restrict__ flag)
{
    __shared__ float sig[HIDDEN];
    __shared__ float red[HIDDEN];
    __shared__ int fl[256];
    const int tid = threadIdx.x;
    if (tid < HIDDEN) {
        float acc = b_in[tid];
        #pragma unroll 8
        for (int d = 0; d < IN_DIM; ++d) acc = fmaf(W_in[tid*IN_DIM + d], x[d], acc);
        sig[tid] = acc;
        red[tid] = fabsf(acc);
    }
    // layout probe: bytes at offset 4k+1 are all 0 iff elements are 4-byte
    int v = 0;
    #pragma unroll
    for (int r = 0; r < 4; ++r) v |= (int)maskb[(tid + 256*r)*4 + 1];
    fl[tid] = v;
    __syncthreads();
    for (int s = 64; s > 0; s >>= 1) {
        if (tid < s) red[tid] = fmaxf(red[tid], red[tid + s]);
        __syncthreads();
    }
    for (int s = 128; s > 0; s >>= 1) {
        if (tid < s) fl[tid] |= fl[tid + s];
        __syncthreads();
    }
    if (tid < HIDDEN) pp[tid] = sig[tid] / (red[0] + 1e-8f) * 0.314159265358979f;
    if (tid == 0) *flag = (fl[0] != 0) ? 1 : 0;   // 1 => 1-byte bool layout
}

// P1: strength[i] = sum_h amp[i,h]
__global__ void k_strength(const float* __restrict__ amp, float* __restrict__ strength)
{
    const int w    = (blockIdx.x * blockDim.x + threadIdx.x) >> 6; // node
    const int lane = threadIdx.x & 63;
    const float2 v = ((const float2*)(amp + (size_t)w * HIDDEN))[lane];
    float s = v.x + v.y;
    #pragma unroll
    for (int off = 32; off > 0; off >>= 1) s += __shfl_xor(s, off);
    if (lane == 0) strength[w] = s;
}

// MAIN: one wave per node, CHUNK nodes per wave; lane owns h = 2*lane, 2*lane+1
__global__ __launch_bounds__(256) void k_main(
    const float* __restrict__ amp, const float* __restrict__ phase,
    const float* __restrict__ vel, const int* __restrict__ nbr_idx,
    const float* __restrict__ nbr_sign, const void* __restrict__ nbr_mask,
    const int* __restrict__ step, const float* __restrict__ pp,
    const int* __restrict__ flagp, const float* __restrict__ strength,
    float* __restrict__ P, float* __restrict__ p_sa, float* __restrict__ p_sa2)
{
    const int wv   = threadIdx.x >> 6;
    const int lane = threadIdx.x & 63;
    const int blk  = blockIdx.x;
    const int w    = blk * WPB + wv;
    const int flag = *flagp;
    const float trev = 0.1f * (float)step[0] * INV2PI;   // wave time in revolutions
    const float pp0 = pp[2*lane], pp1 = pp[2*lane + 1];
    const unsigned char* mb = (const unsigned char*)nbr_mask;
    const int*           mi = (const int*)nbr_mask;

    float accre0=0.f, accre1=0.f, accim0=0.f, accim1=0.f, accsa=0.f, accsa2=0.f;
    const int base = w * CHUNK;

    for (int c = 0; c < CHUNK; ++c) {
        const int i = base + c;
        // ---- wave-uniform per-node prep: mask bits, degree, argmax neighbor ----
        int deg = 0, bslot = -1, mkbits = 0;
        float bstr = -3.0e38f;
        int jidx[MAX_DEG]; float sgn[MAX_DEG];
        #pragma unroll
        for (int k = 0; k < MAX_DEG; ++k) {
            const int e = i*MAX_DEG + k;
            const int m = flag ? (int)mb[e] : (mi[e] != 0);
            jidx[k] = nbr_idx[e];
            sgn[k]  = nbr_sign[e];
            if (m) {
                mkbits |= (1 << k);
                ++deg;
                const float st = strength[jidx[k]];
                if (st > bstr) { bstr = st; bslot = k; }   // strict > keeps first max
            }
        }
        // ---- own state ----
        const float2 av = ((const float2*)(amp   + (size_t)i*HIDDEN))[lane];
        const float2 pv = ((const float2*)(phase + (size_t)i*HIDDEN))[lane];
        const float2 vv = ((const float2*)(vel   + (size_t)i*HIDDEN))[lane];
        float s0,c0,s1,c1;
        fsincos(fmaf(0.1f, vv.x, pv.x), s0, c0);
        fsincos(fmaf(0.1f, vv.y, pv.y), s1, c1);
        const float sr0 = av.x*c0, si0 = av.x*s0, sr1 = av.y*c1, si1 = av.y*s1;

        // ---- neighbor interference ----
        float ir0=0.f, ii0=0.f, ir1=0.f, ii1=0.f;
        float ab0=0.f, cb0=1.f, sb0=0.f, ab1=0.f, cb1=1.f, sb1=0.f;
        #pragma unroll
        for (int k = 0; k < MAX_DEG; ++k) {
            if (!(mkbits & (1 << k))) continue;
            const size_t jo = (size_t)jidx[k]*HIDDEN;
            const float2 aj = ((const float2*)(amp   + jo))[lane];
            const float2 pj = ((const float2*)(phase + jo))[lane];
            const float2 vj = ((const float2*)(vel   + jo))[lane];
            float sj0,cj0,sj1,cj1;
            fsincos(fmaf(0.1f, vj.x, pj.x), sj0, cj0);
            fsincos(fmaf(0.1f, vj.y, pj.y), sj1, cj1);
            const float cpl0 = (c0*cj0 + s0*sj0) * sgn[k];  // cos(a_i - a_j)*sign
            const float cpl1 = (c1*cj1 + s1*sj1) * sgn[k];
            ir0 += cpl0*aj.x*cj0;  ii0 += cpl0*aj.x*sj0;
            ir1 += cpl1*aj.y*cj1;  ii1 += cpl1*aj.y*sj1;
            if (k == bslot) { ab0=aj.x; cb0=cj0; sb0=sj0; ab1=aj.y; cb1=cj1; sb1=sj1; }
        }
        float nr0, ni0, nr1, ni1;
        if (deg > 0) {
            const float invd = 1.0f / (float)deg;
            nr0 = 0.7f*sr0 + (0.3f*(0.1f*ir0))*invd;
            ni0 = 0.7f*si0 + (0.3f*(0.1f*ii0))*invd;
            nr1 = 0.7f*sr1 + (0.3f*(0.1f*ir1))*invd;
            ni1 = 0.7f*si1 + (0.3f*(0.1f*ii1))*invd;
        } else { nr0=sr0; ni0=si0; nr1=sr1; ni1=si1; }

        // ---- morphism toward strongest neighbor ----
        if (deg >= 2) {
            const float g0 = 0.02f * ab0 / sqrtf(nr0*nr0 + ni0*ni0);
            const float mr0 = g0*(nr0*cb0 + ni0*sb0);
            const float mi0 = g0*(ni0*cb0 - nr0*sb0);
            const float g1 = 0.02f * ab1 / sqrtf(nr1*nr1 + ni1*ni1);
            const float mr1 = g1*(nr1*cb1 + ni1*sb1);
            const float mi1 = g1*(ni1*cb1 - nr1*sb1);
            nr0 += mr0; ni0 += mi0; nr1 += mr1; ni1 += mi1;
        }

        // ---- traveling wave (arg in revolutions: t/2pi + i/65536) ----
        const float wr = fmaf((float)i, 1.52587890625e-5f, trev);
        const float wf = 1.0f + 0.02f * __builtin_amdgcn_sinf(wr);
        nr0 *= wf; ni0 *= wf; nr1 *= wf; ni1 *= wf;

        // ---- input-driven phase rotation for i < 32 ----
        if (i < 32) {
            const float fac = 0.1f / fmaf(0.1f, (float)i, 1.0f);
            float sp0,cp0,sp1,cp1;
            fsincos(pp0*fac, sp0, cp0);
            fsincos(pp1*fac, sp1, cp1);
            float tr = nr0*cp0 - ni0*sp0;  ni0 = ni0*cp0 + nr0*sp0;  nr0 = tr;
            tr       = nr1*cp1 - ni1*sp1;  ni1 = ni1*cp1 + nr1*sp1;  nr1 = tr;
        }

        // ---- amplitude renorm: cs = new/(rowmax|new|+1e-8) ----
        const float m0 = sqrtf(nr0*nr0 + ni0*ni0);
        const float m1 = sqrtf(nr1*nr1 + ni1*ni1);
        float lm = fmaxf(m0, m1);
        #pragma unroll
        for (int off = 32; off > 0; off >>= 1) lm = fmaxf(lm, __shfl_xor(lm, off));
        const float sc = 1.0f / (lm + 1e-8f);
        accre0 += nr0*sc; accim0 += ni0*sc;
        accre1 += nr1*sc; accim1 += ni1*sc;
        const float A0 = m0*sc, A1 = m1*sc;
        accsa  += A0 + A1;
        accsa2 += A0*A0 + A1*A1;
    }

    // ---- block-level reduce of partials (4 waves -> 1) ----
    __shared__ float4 lred[WPB][64];
    __shared__ float  lsa[WPB], lsa2[WPB];
    lred[wv][lane] = make_float4(accre0, accre1, accim0, accim1);
    float ss = accsa, ss2 = accsa2;
    #pragma unroll
    for (int off = 32; off > 0; off >>= 1) { ss += __shfl_xor(ss, off); ss2 += __shfl_xor(ss2, off); }
    if (lane == 0) { lsa[wv] = ss; lsa2[wv] = ss2; }
    __syncthreads();
    const int tid = threadIdx.x;
    if (tid < 64) {
        const float4 a = lred[0][tid], b = lred[1][tid], c = lred[2][tid], d = lred[3][tid];
        P[(2*tid  )*NBLK + blk]     = a.x + b.x + c.x + d.x;
        P[(2*tid+1)*NBLK + blk]     = a.y + b.y + c.y + d.y;
        P[(128+2*tid)*NBLK + blk]   = a.z + b.z + c.z + d.z;
        P[(129+2*tid)*NBLK + blk]   = a.w + b.w + c.w + d.w;
    }
    if (tid == 0) {
        p_sa [blk] = lsa[0]  + lsa[1]  + lsa[2]  + lsa[3];
        p_sa2[blk] = lsa2[0] + lsa2[1] + lsa2[2] + lsa2[3];
    }
}

// RED: mean[r] = sum_b P[r][b] / N_CELLS   (256 blocks, coalesced rows)
__global__ void k_red(const float* __restrict__ P, float* __restrict__ mean)
{
    __shared__ double red[256];
    const int r = blockIdx.x, tid = threadIdx.x;
    double s = 0.0;
    #pragma unroll
    for (int k = 0; k < NBLK/256; ++k) s += (double)P[(size_t)r*NBLK + tid + 256*k];
    red[tid] = s;
    __syncthreads();
    for (int st = 128; st > 0; st >>= 1) { if (tid < st) red[tid] += red[tid + st]; __syncthreads(); }
    if (tid == 0) mean[r] = (float)(red[0] / (double)N_CELLS);
}

// FINAL: readout matvec + unbiased variance
__global__ void k_final(const float* __restrict__ mean_in,
                        const float* __restrict__ p_sa, const float* __restrict__ p_sa2,
                        const float* __restrict__ W_dec, const float* __restrict__ b_dec,
                        float* __restrict__ out)
{
    __shared__ float  mean[2*HIDDEN];
    __shared__ double dred[256];
    __shared__ double tots[2];
    const int tid = threadIdx.x;
    mean[tid] = mean_in[tid];
    double sa = 0.0, sa2 = 0.0;
    #pragma unroll
    for (int k = 0; k < NBLK/256; ++k) {
        sa  += (double)p_sa [tid + 256*k];
        sa2 += (double)p_sa2[tid + 256*k];
    }
    dred[tid] = sa;
    __syncthreads();
    for (int s = 128; s > 0; s >>= 1) { if (tid < s) dred[tid] += dred[tid + s]; __syncthreads(); }
    if (tid == 0) tots[0] = dred[0];
    __syncthreads();
    dred[tid] = sa2;
    __syncthreads();
    for (int s = 128; s > 0; s >>= 1) { if (tid < s) dred[tid] += dred[tid + s]; __syncthreads(); }
    if (tid == 0) tots[1] = dred[0];
    __syncthreads();

    if (tid < IN_DIM) {
        float acc = b_dec[tid];
        #pragma unroll 8
        for (int c = 0; c < 2*HIDDEN; ++c) acc = fmaf(mean[c], W_dec[tid*2*HIDDEN + c], acc);
        out[tid] = acc;
    }
    if (tid == 0) {
        const double M = (double)N_CELLS * (double)HIDDEN;
        const double var = (tots[1] - tots[0]*tots[0]/M) / (M - 1.0);
        out[IN_DIM] = (float)var;
    }
}

extern "C" void kernel_launch(void* const* d_in, const int* in_sizes, int n_in,
                              void* d_out, int out_size, void* d_ws, size_t ws_size,
                              hipStream_t stream)
{
    const float* x       = (const float*)d_in[0];
    const float* amp     = (const float*)d_in[1];
    const float* phase   = (const float*)d_in[2];
    const float* vel     = (const float*)d_in[3];
    const int*   nbr_idx = (const int*)d_in[4];
    const float* nbr_sgn = (const float*)d_in[5];
    const void*  nbr_msk = d_in[6];
    const float* W_in    = (const float*)d_in[7];
    const float* b_in    = (const float*)d_in[8];
    const float* W_dec   = (const float*)d_in[9];
    const float* b_dec   = (const float*)d_in[10];
    const int*   step    = (const int*)d_in[11];

    char* wsb = (char*)d_ws;
    float* pp    = (float*)(wsb + WS_PP);
    int*   flag  = (int*)  (wsb + WS_FLAG);
    float* strg  = (float*)(wsb + WS_STR);
    float* P     = (float*)(wsb + WS_P);
    float* p_sa  = (float*)(wsb + WS_SA);
    float* p_sa2 = (float*)(wsb + WS_SA2);
    float* meanb = (float*)(wsb + WS_MEAN);
    float* out   = (float*)d_out;

    k_prep<<<1, 256, 0, stream>>>(x, W_in, b_in, (const unsigned char*)nbr_msk, pp, flag);
    k_strength<<<N_CELLS/4, 256, 0, stream>>>(amp, strg);
    k_main<<<NBLK, 256, 0, stream>>>(amp, phase, vel, nbr_idx, nbr_sgn, nbr_msk,
                                     step, pp, flag, strg, P, p_sa, p_sa2);
    k_red<<<256, 256, 0, stream>>>(P, meanb);
    k_final<<<1, 256, 0, stream>>>(meanb, p_sa, p_sa2, W_dec, b_dec, out);
}

// Round 3
// 89.371 us; speedup vs baseline: 2.4839x; 1.2877x over previous
//
#include <hip/hip_runtime.h>
#include <math.h>

#define N_CELLS 65536
#define HIDDEN  128
#define IN_DIM  64
#define MAX_DEG 6

#define WPB    4                    // waves per block (k_main)
#define NBLK   2048                 // main-kernel blocks
#define NWAVES (NBLK*WPB)           // 8192
#define CHUNK  (N_CELLS/NWAVES)     // 8 nodes per wave

#define INV2PI 0.15915494309189535f

__device__ __forceinline__ void fsincos(float x, float& s, float& c) {
    const float r = x * INV2PI;                     // revolutions for v_sin/v_cos
    s = __builtin_amdgcn_sinf(r);
    c = __builtin_amdgcn_cosf(r);
}

// ---------------- shared ws offsets ----------------
#define WS_PP    0                                  // 128 f32
#define WS_FLAG  512                                // 1 int
#define WS_STR   1024                               // 65536 f32
#define WS_AFT_STR (1024 + N_CELLS*4)

// path A extra:
#define WS_ADJ   WS_AFT_STR                         // 65536*8 int  (2 MB)
#define WS_S     (WS_ADJ + N_CELLS*8*4)             // 65536*128*2 f32 (64 MB)
#define WS_PA    (WS_S + (size_t)N_CELLS*HIDDEN*2*4)// 256*NBLK f32
#define WS_SAA   (WS_PA + 256*NBLK*4)
#define WS_SA2A  (WS_SAA + NBLK*4)
#define WS_MEANA (WS_SA2A + NBLK*4)
#define WS_A_END (WS_MEANA + 1024)

// path B extra (R1 layout):
#define WS_P     WS_AFT_STR
#define WS_SA    (WS_P + 256*NBLK*4)
#define WS_SA2   (WS_SA + NBLK*4)
#define WS_MEAN  (WS_SA2 + NBLK*4)

// P0: sig = W_in @ x + b_in ; pp = sig/(max|sig|+1e-8)*0.1*pi ; mask-layout detect
__global__ void k_prep(const float* __restrict__ x,
                       const float* __restrict__ W_in,
                       const float* __restrict__ b_in,
                       const unsigned char* __restrict__ maskb,
                       float* __restrict__ pp, int* __restrict__ flag)
{
    __shared__ float sig[HIDDEN];
    __shared__ float red[HIDDEN];
    __shared__ int fl[256];
    const int tid = threadIdx.x;
    if (tid < HIDDEN) {
        float acc = b_in[tid];
        #pragma unroll 8
        for (int d = 0; d < IN_DIM; ++d) acc = fmaf(W_in[tid*IN_DIM + d], x[d], acc);
        sig[tid] = acc;
        red[tid] = fabsf(acc);
    }
    int v = 0;
    #pragma unroll
    for (int r = 0; r < 4; ++r) v |= (int)maskb[(tid + 256*r)*4 + 1];
    fl[tid] = v;
    __syncthreads();
    for (int s = 64; s > 0; s >>= 1) {
        if (tid < s) red[tid] = fmaxf(red[tid], red[tid + s]);
        __syncthreads();
    }
    for (int s = 128; s > 0; s >>= 1) {
        if (tid < s) fl[tid] |= fl[tid + s];
        __syncthreads();
    }
    if (tid < HIDDEN) pp[tid] = sig[tid] / (red[0] + 1e-8f) * 0.314159265358979f;
    if (tid == 0) *flag = (fl[0] != 0) ? 1 : 0;   // 1 => 1-byte bool layout
}

// ============================= PATH A =============================
// k_pre: S[i][h] = (R,I) = amp*e^{i(phase+0.1 vel)}; strength[i] = sum_h amp
// 8 nodes/block: half-wave (32 lanes) per node, 4 h per thread.
__global__ __launch_bounds__(256) void k_pre(
    const float* __restrict__ amp, const float* __restrict__ phase,
    const float* __restrict__ vel, float* __restrict__ S,
    float* __restrict__ strength)
{
    const int t   = threadIdx.x;
    const int wv  = t >> 6;
    const int lane= t & 63;
    const int hl  = lane & 31;
    const int i   = blockIdx.x*8 + wv*2 + (lane >> 5);
    const size_t ro = (size_t)i*HIDDEN + 4*hl;
    const float4 a = *(const float4*)(amp   + ro);
    const float4 p = *(const float4*)(phase + ro);
    const float4 v = *(const float4*)(vel   + ro);
    float s0,c0,s1,c1,s2,c2,s3,c3;
    fsincos(fmaf(0.1f, v.x, p.x), s0, c0);
    fsincos(fmaf(0.1f, v.y, p.y), s1, c1);
    fsincos(fmaf(0.1f, v.z, p.z), s2, c2);
    fsincos(fmaf(0.1f, v.w, p.w), s3, c3);
    float* dst = S + (size_t)i*HIDDEN*2 + 8*hl;
    ((float4*)dst)[0] = make_float4(a.x*c0, a.x*s0, a.y*c1, a.y*s1);
    ((float4*)dst)[1] = make_float4(a.z*c2, a.z*s2, a.w*c3, a.w*s3);
    float st = a.x + a.y + a.z + a.w;
    #pragma unroll
    for (int off = 16; off > 0; off >>= 1) st += __shfl_xor(st, off);
    if (hl == 0) strength[i] = st;
}

// k_adj: packed adjacency: per node 8 ints {w0..w5, deg, bslot};
// w = j | (signbit<<24) | (valid<<25); invalid slot -> 0 (row 0, sgn 0)
__global__ void k_adj(const int* __restrict__ nbr_idx,
                      const float* __restrict__ nbr_sign,
                      const void* __restrict__ nbr_mask,
                      const int* __restrict__ flagp,
                      const float* __restrict__ strength,
                      int* __restrict__ adj)
{
    const int i = blockIdx.x*256 + threadIdx.x;
    const int flag = *flagp;
    const unsigned char* mb = (const unsigned char*)nbr_mask;
    const int*           mi = (const int*)nbr_mask;
    int w[MAX_DEG];
    int deg = 0, bslot = 0;
    float bstr = -3.0e38f;
    #pragma unroll
    for (int k = 0; k < MAX_DEG; ++k) {
        const int e = i*MAX_DEG + k;
        const int m = flag ? (mb[e] != 0) : (mi[e] != 0);
        const int j = nbr_idx[e];
        const float sg = nbr_sign[e];
        w[k] = m ? (j | ((sg < 0.0f) ? (1<<24) : 0) | (1<<25)) : 0;
        if (m) {
            ++deg;
            const float st = strength[j];
            if (st > bstr) { bstr = st; bslot = k; }   // strict > keeps first max
        }
    }
    int* dst = adj + (size_t)i*8;
    ((int4*)dst)[0] = make_int4(w[0], w[1], w[2], w[3]);
    ((int4*)dst)[1] = make_int4(w[4], w[5], deg, bslot);
}

// k_main A: branchless gathers from S; no transcendentals in edge loop.
__global__ __launch_bounds__(256) void k_main_a(
    const float* __restrict__ S, const int* __restrict__ adj,
    const int* __restrict__ step, const float* __restrict__ pp,
    float* __restrict__ P, float* __restrict__ p_sa, float* __restrict__ p_sa2)
{
    const int wv   = threadIdx.x >> 6;
    const int lane = threadIdx.x & 63;
    const int blk  = blockIdx.x;
    const int w    = blk * WPB + wv;
    const float trev = 0.1f * (float)step[0] * INV2PI;
    const float pp0 = pp[2*lane], pp1 = pp[2*lane + 1];

    float accre0=0.f, accre1=0.f, accim0=0.f, accim1=0.f, accsa=0.f, accsa2=0.f;
    const int base = w * CHUNK;

    for (int c = 0; c < CHUNK; ++c) {
        const int i  = base + c;
        const int iu = __builtin_amdgcn_readfirstlane(i);
        const int4 A0 = ((const int4*)(adj + (size_t)iu*8))[0];
        const int4 A1 = ((const int4*)(adj + (size_t)iu*8))[1];
        const float4 Si = *(const float4*)(S + (size_t)i*HIDDEN*2 + 4*lane);
        const int deg = A1.z, bslot = A1.w;

        const float inva0 = __builtin_amdgcn_rsqf(Si.x*Si.x + Si.y*Si.y);
        const float inva1 = __builtin_amdgcn_rsqf(Si.z*Si.z + Si.w*Si.w);

        float ir0=0.f, ii0=0.f, ir1=0.f, ii1=0.f;
        float Rb0=0.f, Ib0=0.f, Rb1=0.f, Ib1=0.f;
        const int slots[MAX_DEG] = {A0.x, A0.y, A0.z, A0.w, A1.x, A1.y};
        #pragma unroll
        for (int k = 0; k < MAX_DEG; ++k) {
            const int v = slots[k];
            const int j = v & 0xFFFFF;
            const float sgnm = (v & (1<<25)) ? ((v & (1<<24)) ? -1.0f : 1.0f) : 0.0f;
            const float4 Sj = *(const float4*)(S + (size_t)j*HIDDEN*2 + 4*lane);
            const float E0 = Si.x*Sj.x + Si.y*Sj.y;     // a_i a_j cos(di-dj)
            const float E1 = Si.z*Sj.z + Si.w*Sj.w;
            const float g0 = sgnm * E0 * __builtin_amdgcn_rsqf(Sj.x*Sj.x + Sj.y*Sj.y);
            const float g1 = sgnm * E1 * __builtin_amdgcn_rsqf(Sj.z*Sj.z + Sj.w*Sj.w);
            ir0 = fmaf(g0, Sj.x, ir0);  ii0 = fmaf(g0, Sj.y, ii0);
            ir1 = fmaf(g1, Sj.z, ir1);  ii1 = fmaf(g1, Sj.w, ii1);
            if (k == bslot) { Rb0=Sj.x; Ib0=Sj.y; Rb1=Sj.z; Ib1=Sj.w; }
        }

        // new = 0.7*state + 0.3*0.1*interference/deg  (deg >= 1 always)
        const float invd = 1.0f / (float)deg;
        const float f0 = 0.03f * invd * inva0;
        const float f1 = 0.03f * invd * inva1;
        float nr0 = fmaf(0.7f, Si.x, f0*ir0);
        float ni0 = fmaf(0.7f, Si.y, f0*ii0);
        float nr1 = fmaf(0.7f, Si.z, f1*ir1);
        float ni1 = fmaf(0.7f, Si.w, f1*ii1);

        // morphism toward strongest neighbor (|src| cancels)
        if (deg >= 2) {
            const float im0 = 0.02f * __builtin_amdgcn_rsqf(nr0*nr0 + ni0*ni0);
            const float im1 = 0.02f * __builtin_amdgcn_rsqf(nr1*nr1 + ni1*ni1);
            const float mr0 = im0*(nr0*Rb0 + ni0*Ib0);
            const float mi0 = im0*(ni0*Rb0 - nr0*Ib0);
            const float mr1 = im1*(nr1*Rb1 + ni1*Ib1);
            const float mi1 = im1*(ni1*Rb1 - nr1*Ib1);
            nr0 += mr0; ni0 += mi0; nr1 += mr1; ni1 += mi1;
        }

        // traveling wave
        const float wr = fmaf((float)i, 1.52587890625e-5f, trev);
        const float wf = 1.0f + 0.02f * __builtin_amdgcn_sinf(wr);
        nr0 *= wf; ni0 *= wf; nr1 *= wf; ni1 *= wf;

        // input-driven phase rotation for i < 32
        if (i < 32) {
            const float fac = 0.1f / fmaf(0.1f, (float)i, 1.0f);
            float sp0,cp0,sp1,cp1;
            fsincos(pp0*fac, sp0, cp0);
            fsincos(pp1*fac, sp1, cp1);
            float tr = nr0*cp0 - ni0*sp0;  ni0 = ni0*cp0 + nr0*sp0;  nr0 = tr;
            tr       = nr1*cp1 - ni1*sp1;  ni1 = ni1*cp1 + nr1*sp1;  nr1 = tr;
        }

        // amplitude renorm
        const float m0 = sqrtf(nr0*nr0 + ni0*ni0);
        const float m1 = sqrtf(nr1*nr1 + ni1*ni1);
        float lm = fmaxf(m0, m1);
        #pragma unroll
        for (int off = 32; off > 0; off >>= 1) lm = fmaxf(lm, __shfl_xor(lm, off));
        const float sc = 1.0f / (lm + 1e-8f);
        accre0 += nr0*sc; accim0 += ni0*sc;
        accre1 += nr1*sc; accim1 += ni1*sc;
        const float A0v = m0*sc, A1v = m1*sc;
        accsa  += A0v + A1v;
        accsa2 += A0v*A0v + A1v*A1v;
    }

    __shared__ float4 lred[WPB][64];
    __shared__ float  lsa[WPB], lsa2[WPB];
    lred[wv][lane] = make_float4(accre0, accre1, accim0, accim1);
    float ss = accsa, ss2 = accsa2;
    #pragma unroll
    for (int off = 32; off > 0; off >>= 1) { ss += __shfl_xor(ss, off); ss2 += __shfl_xor(ss2, off); }
    if (lane == 0) { lsa[wv] = ss; lsa2[wv] = ss2; }
    __syncthreads();
    const int tid = threadIdx.x;
    if (tid < 64) {
        const float4 a = lred[0][tid], b = lred[1][tid], c = lred[2][tid], d = lred[3][tid];
        P[(2*tid  )*NBLK + blk]     = a.x + b.x + c.x + d.x;
        P[(2*tid+1)*NBLK + blk]     = a.y + b.y + c.y + d.y;
        P[(128+2*tid)*NBLK + blk]   = a.z + b.z + c.z + d.z;
        P[(129+2*tid)*NBLK + blk]   = a.w + b.w + c.w + d.w;
    }
    if (tid == 0) {
        p_sa [blk] = lsa[0]  + lsa[1]  + lsa[2]  + lsa[3];
        p_sa2[blk] = lsa2[0] + lsa2[1] + lsa2[2] + lsa2[3];
    }
}

// ============================= PATH B (R1 fallback) =============================
__global__ void k_strength(const float* __restrict__ amp, float* __restrict__ strength)
{
    const int w    = (blockIdx.x * blockDim.x + threadIdx.x) >> 6;
    const int lane = threadIdx.x & 63;
    const float2 v = ((const float2*)(amp + (size_t)w * HIDDEN))[lane];
    float s = v.x + v.y;
    #pragma unroll
    for (int off = 32; off > 0; off >>= 1) s += __shfl_xor(s, off);
    if (lane == 0) strength[w] = s;
}

__global__ __launch_bounds__(256) void k_main_b(
    const float* __restrict__ amp, const float* __restrict__ phase,
    const float* __restrict__ vel, const int* __restrict__ nbr_idx,
    const float* __restrict__ nbr_sign, const void* __restrict__ nbr_mask,
    const int* __restrict__ step, const float* __restrict__ pp,
    const int* __restrict__ flagp, const float* __restrict__ strength,
    float* __restrict__ P, float* __restrict__ p_sa, float* __restrict__ p_sa2)
{
    const int wv   = threadIdx.x >> 6;
    const int lane = threadIdx.x & 63;
    const int blk  = blockIdx.x;
    const int w    = blk * WPB + wv;
    const int flag = *flagp;
    const float trev = 0.1f * (float)step[0] * INV2PI;
    const float pp0 = pp[2*lane], pp1 = pp[2*lane + 1];
    const unsigned char* mb = (const unsigned char*)nbr_mask;
    const int*           mi = (const int*)nbr_mask;

    float accre0=0.f, accre1=0.f, accim0=0.f, accim1=0.f, accsa=0.f, accsa2=0.f;
    const int base = w * CHUNK;

    for (int c = 0; c < CHUNK; ++c) {
        const int i = base + c;
        int deg = 0, bslot = -1, mkbits = 0;
        float bstr = -3.0e38f;
        int jidx[MAX_DEG]; float sgn[MAX_DEG];
        #pragma unroll
        for (int k = 0; k < MAX_DEG; ++k) {
            const int e = i*MAX_DEG + k;
            const int m = flag ? (int)mb[e] : (mi[e] != 0);
            jidx[k] = nbr_idx[e];
            sgn[k]  = nbr_sign[e];
            if (m) {
                mkbits |= (1 << k);
                ++deg;
                const float st = strength[jidx[k]];
                if (st > bstr) { bstr = st; bslot = k; }
            }
        }
        const float2 av = ((const float2*)(amp   + (size_t)i*HIDDEN))[lane];
        const float2 pv = ((const float2*)(phase + (size_t)i*HIDDEN))[lane];
        const float2 vv = ((const float2*)(vel   + (size_t)i*HIDDEN))[lane];
        float s0,c0,s1,c1;
        fsincos(fmaf(0.1f, vv.x, pv.x), s0, c0);
        fsincos(fmaf(0.1f, vv.y, pv.y), s1, c1);
        const float sr0 = av.x*c0, si0 = av.x*s0, sr1 = av.y*c1, si1 = av.y*s1;

        float ir0=0.f, ii0=0.f, ir1=0.f, ii1=0.f;
        float ab0=0.f, cb0=1.f, sb0=0.f, ab1=0.f, cb1=1.f, sb1=0.f;
        #pragma unroll
        for (int k = 0; k < MAX_DEG; ++k) {
            if (!(mkbits & (1 << k))) continue;
            const size_t jo = (size_t)jidx[k]*HIDDEN;
            const float2 aj = ((const float2*)(amp   + jo))[lane];
            const float2 pj = ((const float2*)(phase + jo))[lane];
            const float2 vj = ((const float2*)(vel   + jo))[lane];
            float sj0,cj0,sj1,cj1;
            fsincos(fmaf(0.1f, vj.x, pj.x), sj0, cj0);
            fsincos(fmaf(0.1f, vj.y, pj.y), sj1, cj1);
            const float cpl0 = (c0*cj0 + s0*sj0) * sgn[k];
            const float cpl1 = (c1*cj1 + s1*sj1) * sgn[k];
            ir0 += cpl0*aj.x*cj0;  ii0 += cpl0*aj.x*sj0;
            ir1 += cpl1*aj.y*cj1;  ii1 += cpl1*aj.y*sj1;
            if (k == bslot) { ab0=aj.x; cb0=cj0; sb0=sj0; ab1=aj.y; cb1=cj1; sb1=sj1; }
        }
        float nr0, ni0, nr1, ni1;
        if (deg > 0) {
            const float invd = 1.0f / (float)deg;
            nr0 = 0.7f*sr0 + (0.3f*(0.1f*ir0))*invd;
            ni0 = 0.7f*si0 + (0.3f*(0.1f*ii0))*invd;
            nr1 = 0.7f*sr1 + (0.3f*(0.1f*ir1))*invd;
            ni1 = 0.7f*si1 + (0.3f*(0.1f*ii1))*invd;
        } else { nr0=sr0; ni0=si0; nr1=sr1; ni1=si1; }

        if (deg >= 2) {
            const float g0 = 0.02f * ab0 / sqrtf(nr0*nr0 + ni0*ni0);
            const float mr0 = g0*(nr0*cb0 + ni0*sb0);
            const float mi0 = g0*(ni0*cb0 - nr0*sb0);
            const float g1 = 0.02f * ab1 / sqrtf(nr1*nr1 + ni1*ni1);
            const float mr1 = g1*(nr1*cb1 + ni1*sb1);
            const float mi1 = g1*(ni1*cb1 - nr1*sb1);
            nr0 += mr0; ni0 += mi0; nr1 += mr1; ni1 += mi1;
        }

        const float wr = fmaf((float)i, 1.52587890625e-5f, trev);
        const float wf = 1.0f + 0.02f * __builtin_amdgcn_sinf(wr);
        nr0 *= wf; ni0 *= wf; nr1 *= wf; ni1 *= wf;

        if (i < 32) {
            const float fac = 0.1f / fmaf(0.1f, (float)i, 1.0f);
            float sp0,cp0,sp1,cp1;
            fsincos(pp0*fac, sp0, cp0);
            fsincos(pp1*fac, sp1, cp1);
            float tr = nr0*cp0 - ni0*sp0;  ni0 = ni0*cp0 + nr0*sp0;  nr0 = tr;
            tr       = nr1*cp1 - ni1*sp1;  ni1 = ni1*cp1 + nr1*sp1;  nr1 = tr;
        }

        const float m0 = sqrtf(nr0*nr0 + ni0*ni0);
        const float m1 = sqrtf(nr1*nr1 + ni1*ni1);
        float lm = fmaxf(m0, m1);
        #pragma unroll
        for (int off = 32; off > 0; off >>= 1) lm = fmaxf(lm, __shfl_xor(lm, off));
        const float sc = 1.0f / (lm + 1e-8f);
        accre0 += nr0*sc; accim0 += ni0*sc;
        accre1 += nr1*sc; accim1 += ni1*sc;
        const float A0 = m0*sc, A1 = m1*sc;
        accsa  += A0 + A1;
        accsa2 += A0*A0 + A1*A1;
    }

    __shared__ float4 lred[WPB][64];
    __shared__ float  lsa[WPB], lsa2[WPB];
    lred[wv][lane] = make_float4(accre0, accre1, accim0, accim1);
    float ss = accsa, ss2 = accsa2;
    #pragma unroll
    for (int off = 32; off > 0; off >>= 1) { ss += __shfl_xor(ss, off); ss2 += __shfl_xor(ss2, off); }
    if (lane == 0) { lsa[wv] = ss; lsa2[wv] = ss2; }
    __syncthreads();
    const int tid = threadIdx.x;
    if (tid < 64) {
        const float4 a = lred[0][tid], b = lred[1][tid], c = lred[2][tid], d = lred[3][tid];
        P[(2*tid  )*NBLK + blk]     = a.x + b.x + c.x + d.x;
        P[(2*tid+1)*NBLK + blk]     = a.y + b.y + c.y + d.y;
        P[(128+2*tid)*NBLK + blk]   = a.z + b.z + c.z + d.z;
        P[(129+2*tid)*NBLK + blk]   = a.w + b.w + c.w + d.w;
    }
    if (tid == 0) {
        p_sa [blk] = lsa[0]  + lsa[1]  + lsa[2]  + lsa[3];
        p_sa2[blk] = lsa2[0] + lsa2[1] + lsa2[2] + lsa2[3];
    }
}

// ---------------- reductions ----------------
__global__ void k_red(const float* __restrict__ P, float* __restrict__ mean)
{
    __shared__ double red[256];
    const int r = blockIdx.x, tid = threadIdx.x;
    double s = 0.0;
    #pragma unroll
    for (int k = 0; k < NBLK/256; ++k) s += (double)P[(size_t)r*NBLK + tid + 256*k];
    red[tid] = s;
    __syncthreads();
    for (int st = 128; st > 0; st >>= 1) { if (tid < st) red[tid] += red[tid + st]; __syncthreads(); }
    if (tid == 0) mean[r] = (float)(red[0] / (double)N_CELLS);
}

__global__ void k_final(const float* __restrict__ mean_in,
                        const float* __restrict__ p_sa, const float* __restrict__ p_sa2,
                        const float* __restrict__ W_dec, const float* __restrict__ b_dec,
                        float* __restrict__ out)
{
    __shared__ float  mean[2*HIDDEN];
    __shared__ double dred[256];
    __shared__ double tots[2];
    const int tid = threadIdx.x;
    mean[tid] = mean_in[tid];
    double sa = 0.0, sa2 = 0.0;
    #pragma unroll
    for (int k = 0; k < NBLK/256; ++k) {
        sa  += (double)p_sa [tid + 256*k];
        sa2 += (double)p_sa2[tid + 256*k];
    }
    dred[tid] = sa;
    __syncthreads();
    for (int s = 128; s > 0; s >>= 1) { if (tid < s) dred[tid] += dred[tid + s]; __syncthreads(); }
    if (tid == 0) tots[0] = dred[0];
    __syncthreads();
    dred[tid] = sa2;
    __syncthreads();
    for (int s = 128; s > 0; s >>= 1) { if (tid < s) dred[tid] += dred[tid + s]; __syncthreads(); }
    if (tid == 0) tots[1] = dred[0];
    __syncthreads();

    if (tid < IN_DIM) {
        float acc = b_dec[tid];
        #pragma unroll 8
        for (int c = 0; c < 2*HIDDEN; ++c) acc = fmaf(mean[c], W_dec[tid*2*HIDDEN + c], acc);
        out[tid] = acc;
    }
    if (tid == 0) {
        const double M = (double)N_CELLS * (double)HIDDEN;
        const double var = (tots[1] - tots[0]*tots[0]/M) / (M - 1.0);
        out[IN_DIM] = (float)var;
    }
}

extern "C" void kernel_launch(void* const* d_in, const int* in_sizes, int n_in,
                              void* d_out, int out_size, void* d_ws, size_t ws_size,
                              hipStream_t stream)
{
    const float* x       = (const float*)d_in[0];
    const float* amp     = (const float*)d_in[1];
    const float* phase   = (const float*)d_in[2];
    const float* vel     = (const float*)d_in[3];
    const int*   nbr_idx = (const int*)d_in[4];
    const float* nbr_sgn = (const float*)d_in[5];
    const void*  nbr_msk = d_in[6];
    const float* W_in    = (const float*)d_in[7];
    const float* b_in    = (const float*)d_in[8];
    const float* W_dec   = (const float*)d_in[9];
    const float* b_dec   = (const float*)d_in[10];
    const int*   step    = (const int*)d_in[11];

    char* wsb = (char*)d_ws;
    float* pp    = (float*)(wsb + WS_PP);
    int*   flag  = (int*)  (wsb + WS_FLAG);
    float* strg  = (float*)(wsb + WS_STR);
    float* out   = (float*)d_out;

    k_prep<<<1, 256, 0, stream>>>(x, W_in, b_in, (const unsigned char*)nbr_msk, pp, flag);

    if (ws_size >= (size_t)WS_A_END) {
        // -------- path A --------
        int*   adj   = (int*)  (wsb + WS_ADJ);
        float* S     = (float*)(wsb + WS_S);
        float* P     = (float*)(wsb + WS_PA);
        float* p_sa  = (float*)(wsb + WS_SAA);
        float* p_sa2 = (float*)(wsb + WS_SA2A);
        float* meanb = (float*)(wsb + WS_MEANA);
        k_pre<<<N_CELLS/8, 256, 0, stream>>>(amp, phase, vel, S, strg);
        k_adj<<<N_CELLS/256, 256, 0, stream>>>(nbr_idx, nbr_sgn, nbr_msk, flag, strg, adj);
        k_main_a<<<NBLK, 256, 0, stream>>>(S, adj, step, pp, P, p_sa, p_sa2);
        k_red<<<256, 256, 0, stream>>>(P, meanb);
        k_final<<<1, 256, 0, stream>>>(meanb, p_sa, p_sa2, W_dec, b_dec, out);
    } else {
        // -------- path B (R1) --------
        float* P     = (float*)(wsb + WS_P);
        float* p_sa  = (float*)(wsb + WS_SA);
        float* p_sa2 = (float*)(wsb + WS_SA2);
        float* meanb = (float*)(wsb + WS_MEAN);
        k_strength<<<N_CELLS/4, 256, 0, stream>>>(amp, strg);
        k_main_b<<<NBLK, 256, 0, stream>>>(amp, phase, vel, nbr_idx, nbr_sgn, nbr_msk,
                                           step, pp, flag, strg, P, p_sa, p_sa2);
        k_red<<<256, 256, 0, stream>>>(P, meanb);
        k_final<<<1, 256, 0, stream>>>(meanb, p_sa, p_sa2, W_dec, b_dec, out);
    }
}

// Round 4
// 78.936 us; speedup vs baseline: 2.8122x; 1.1322x over previous
//
#include <hip/hip_runtime.h>
#include <math.h>

#define N_CELLS 65536
#define HIDDEN  128
#define IN_DIM  64
#define MAX_DEG 6

#define WPB    4                    // waves per block (k_main)
#define NPB    32                   // nodes per block = WPB * CHUNK
#define NBLK   (N_CELLS/NPB)        // 2048 main-kernel blocks
#define CHUNK  8                    // nodes per wave

#define INV2PI 0.15915494309189535f

__device__ __forceinline__ void fsincos(float x, float& s, float& c) {
    const float r = x * INV2PI;                     // revolutions for v_sin/v_cos
    s = __builtin_amdgcn_sinf(r);
    c = __builtin_amdgcn_cosf(r);
}

// ---------------- ws offsets (~2.3 MB) ----------------
#define WS_PP    0                                  // 128 f32
#define WS_FLAG  512                                // 1 int
#define WS_STR   1024                               // 65536 f32
#define WS_P     (1024 + N_CELLS*4)                 // 256 x NBLK f32
#define WS_SA    (WS_P + 256*NBLK*4)                // NBLK f32
#define WS_SA2   (WS_SA + NBLK*4)                   // NBLK f32
#define WS_MEAN  (WS_SA2 + NBLK*4)                  // 256 f32

// k_sp: strength[i] = sum_h amp[i,h] (blocks 0..N/4-1); prep (last block):
//   sig = W_in@x + b_in; pp = sig/(max|sig|+1e-8)*0.1*pi; mask-layout detect.
__global__ __launch_bounds__(256) void k_sp(
    const float* __restrict__ amp, float* __restrict__ strength,
    const float* __restrict__ x, const float* __restrict__ W_in,
    const float* __restrict__ b_in, const unsigned char* __restrict__ maskb,
    float* __restrict__ pp, int* __restrict__ flag)
{
    const int tid = threadIdx.x;
    if (blockIdx.x < N_CELLS/4) {
        const int node = blockIdx.x*4 + (tid >> 6);
        const int lane = tid & 63;
        const float2 v = ((const float2*)(amp + (size_t)node*HIDDEN))[lane];
        float s = v.x + v.y;
        #pragma unroll
        for (int off = 32; off > 0; off >>= 1) s += __shfl_xor(s, off);
        if (lane == 0) strength[node] = s;
        return;
    }
    __shared__ float sig[HIDDEN];
    __shared__ float red[HIDDEN];
    __shared__ int fl[256];
    if (tid < HIDDEN) {
        float acc = b_in[tid];
        #pragma unroll 8
        for (int d = 0; d < IN_DIM; ++d) acc = fmaf(W_in[tid*IN_DIM + d], x[d], acc);
        sig[tid] = acc;
        red[tid] = fabsf(acc);
    }
    int v = 0;
    #pragma unroll
    for (int r = 0; r < 4; ++r) v |= (int)maskb[(tid + 256*r)*4 + 1];
    fl[tid] = v;
    __syncthreads();
    for (int s = 64; s > 0; s >>= 1) {
        if (tid < s) red[tid] = fmaxf(red[tid], red[tid + s]);
        __syncthreads();
    }
    for (int s = 128; s > 0; s >>= 1) {
        if (tid < s) fl[tid] |= fl[tid + s];
        __syncthreads();
    }
    if (tid < HIDDEN) pp[tid] = sig[tid] / (red[0] + 1e-8f) * 0.314159265358979f;
    if (tid == 0) *flag = (fl[0] != 0) ? 1 : 0;   // 1 => 1-byte bool layout
}

// MAIN: 32 nodes/block. Prologue builds packed adjacency + argmax in LDS.
// Main loop: branchless 6-slot gathers of (amp,phase,vel), HW sincos, no S array.
__global__ __launch_bounds__(256) void k_main2(
    const float* __restrict__ amp, const float* __restrict__ phase,
    const float* __restrict__ vel, const int* __restrict__ nbr_idx,
    const float* __restrict__ nbr_sign, const void* __restrict__ nbr_mask,
    const int* __restrict__ step, const float* __restrict__ pp,
    const int* __restrict__ flagp, const float* __restrict__ strength,
    float* __restrict__ P, float* __restrict__ p_sa, float* __restrict__ p_sa2)
{
    __shared__ int   lwp[NPB][8];    // [0..5]=word j|sign<<24|valid<<25, [6]=deg, [7]=jb
    __shared__ float lsk[NPB][6];    // argmax keys
    const int tid  = threadIdx.x;
    const int blk  = blockIdx.x;
    const int node0 = blk * NPB;

    // ---- prologue: adjacency pack + argmax (ex-k_adj) ----
    {
        const int flag = *flagp;
        const unsigned char* mb = (const unsigned char*)nbr_mask;
        const int*           mi = (const int*)nbr_mask;
        if (tid < NPB*MAX_DEG) {
            const int n = tid / MAX_DEG, k = tid - n*MAX_DEG;
            const int e = (node0 + n)*MAX_DEG + k;
            const int m = flag ? (mb[e] != 0) : (mi[e] != 0);
            const int j = nbr_idx[e];
            const float sg = nbr_sign[e];
            lwp[n][k] = m ? (j | ((sg < 0.0f) ? (1<<24) : 0) | (1<<25)) : 0;
            lsk[n][k] = m ? strength[j] : -3.0e38f;
        }
    }
    __syncthreads();
    if (tid < NPB) {
        int deg = 0, bs = 0; float bv = -3.0e38f;
        #pragma unroll
        for (int k = 0; k < MAX_DEG; ++k) {
            deg += (lwp[tid][k] >> 25) & 1;
            const float sv = lsk[tid][k];
            if (sv > bv) { bv = sv; bs = k; }          // strict > keeps first max
        }
        lwp[tid][6] = deg;
        lwp[tid][7] = lwp[tid][bs] & 0xFFFFF;          // best neighbor index
    }
    __syncthreads();

    const int wv   = tid >> 6;
    const int lane = tid & 63;
    const float trev = 0.1f * (float)step[0] * INV2PI;
    const float2 ppv = ((const float2*)pp)[lane];
    const unsigned loff = (unsigned)lane * 8u;          // byte offset of lane's float2

    float accre0=0.f, accre1=0.f, accim0=0.f, accim1=0.f, accsa=0.f, accsa2=0.f;

    for (int c = 0; c < CHUNK; ++c) {
        const int nl = wv*CHUNK + c;
        const int i  = node0 + nl;
        const int4 A0 = *(const int4*)&lwp[nl][0];
        const int4 A1 = *(const int4*)&lwp[nl][4];
        const int deg = A1.z, jb = A1.w;

        // own state
        const unsigned io = (unsigned)i*512u + loff;
        const float2 av = *(const float2*)((const char*)amp   + io);
        const float2 pv = *(const float2*)((const char*)phase + io);
        const float2 vv = *(const float2*)((const char*)vel   + io);
        float s0,c0,s1,c1;
        fsincos(fmaf(0.1f, vv.x, pv.x), s0, c0);
        fsincos(fmaf(0.1f, vv.y, pv.y), s1, c1);
        const float Ri0 = av.x*c0, Ii0 = av.x*s0, Ri1 = av.y*c1, Ii1 = av.y*s1;

        // ---- neighbor interference (branchless 6 slots) ----
        float ir0=0.f, ii0=0.f, ir1=0.f, ii1=0.f;
        const int slots[MAX_DEG] = {A0.x, A0.y, A0.z, A0.w, A1.x, A1.y};
        #pragma unroll
        for (int k = 0; k < MAX_DEG; ++k) {
            const int w = slots[k];
            const unsigned j = (unsigned)(w & 0xFFFFF);
            const float sgnm = (w & (1<<25)) ? ((w & (1<<24)) ? -1.0f : 1.0f) : 0.0f;
            const unsigned jo = j*512u + loff;
            const float2 aj = *(const float2*)((const char*)amp   + jo);
            const float2 pj = *(const float2*)((const char*)phase + jo);
            const float2 vj = *(const float2*)((const char*)vel   + jo);
            float sj0,cj0,sj1,cj1;
            fsincos(fmaf(0.1f, vj.x, pj.x), sj0, cj0);
            fsincos(fmaf(0.1f, vj.y, pj.y), sj1, cj1);
            const float t0 = (c0*cj0 + s0*sj0) * (sgnm * aj.x);   // cosD * sgn * a_j
            const float t1 = (c1*cj1 + s1*sj1) * (sgnm * aj.y);
            ir0 = fmaf(t0, cj0, ir0);  ii0 = fmaf(t0, sj0, ii0);
            ir1 = fmaf(t1, cj1, ir1);  ii1 = fmaf(t1, sj1, ii1);
        }

        // new = 0.7*state + (0.3*0.1/deg)*interference   (deg >= 1 always)
        const float f = 0.03f * __builtin_amdgcn_rcpf((float)deg);
        float nr0 = fmaf(0.7f, Ri0, f*ir0);
        float ni0 = fmaf(0.7f, Ii0, f*ii0);
        float nr1 = fmaf(0.7f, Ri1, f*ir1);
        float ni1 = fmaf(0.7f, Ii1, f*ii1);

        // ---- morphism: new += 0.02 * new*conj(src)/|new| ----
        if (deg >= 2) {
            const unsigned bo = (unsigned)jb*512u + loff;
            const float2 ab = *(const float2*)((const char*)amp   + bo);
            const float2 pb = *(const float2*)((const char*)phase + bo);
            const float2 vb = *(const float2*)((const char*)vel   + bo);
            float sb0,cb0,sb1,cb1;
            fsincos(fmaf(0.1f, vb.x, pb.x), sb0, cb0);
            fsincos(fmaf(0.1f, vb.y, pb.y), sb1, cb1);
            const float Rb0 = ab.x*cb0, Ib0 = ab.x*sb0;
            const float Rb1 = ab.y*cb1, Ib1 = ab.y*sb1;
            const float im0 = 0.02f * __builtin_amdgcn_rsqf(nr0*nr0 + ni0*ni0);
            const float im1 = 0.02f * __builtin_amdgcn_rsqf(nr1*nr1 + ni1*ni1);
            const float mr0 = im0*(nr0*Rb0 + ni0*Ib0);
            const float mi0 = im0*(ni0*Rb0 - nr0*Ib0);
            const float mr1 = im1*(nr1*Rb1 + ni1*Ib1);
            const float mi1 = im1*(ni1*Rb1 - nr1*Ib1);
            nr0 += mr0; ni0 += mi0; nr1 += mr1; ni1 += mi1;
        }

        // ---- traveling wave ----
        const float wr = fmaf((float)i, 1.52587890625e-5f, trev);
        const float wf = 1.0f + 0.02f * __builtin_amdgcn_sinf(wr);
        nr0 *= wf; ni0 *= wf; nr1 *= wf; ni1 *= wf;

        // ---- input-driven phase rotation for i < 32 ----
        if (i < 32) {
            const float fac = 0.1f / fmaf(0.1f, (float)i, 1.0f);
            float sp0,cp0,sp1,cp1;
            fsincos(ppv.x*fac, sp0, cp0);
            fsincos(ppv.y*fac, sp1, cp1);
            float tr = nr0*cp0 - ni0*sp0;  ni0 = ni0*cp0 + nr0*sp0;  nr0 = tr;
            tr       = nr1*cp1 - ni1*sp1;  ni1 = ni1*cp1 + nr1*sp1;  nr1 = tr;
        }

        // ---- amplitude renorm: cs = new/(rowmax|new|+1e-8) ----
        const float m0 = sqrtf(nr0*nr0 + ni0*ni0);
        const float m1 = sqrtf(nr1*nr1 + ni1*ni1);
        float lm = fmaxf(m0, m1);
        #pragma unroll
        for (int off = 32; off > 0; off >>= 1) lm = fmaxf(lm, __shfl_xor(lm, off));
        const float sc = 1.0f / (lm + 1e-8f);
        accre0 += nr0*sc; accim0 += ni0*sc;
        accre1 += nr1*sc; accim1 += ni1*sc;
        const float Aa = m0*sc, Ab = m1*sc;
        accsa  += Aa + Ab;
        accsa2 += Aa*Aa + Ab*Ab;
    }

    // ---- block-level reduce of partials ----
    __shared__ float4 lred[WPB][64];
    __shared__ float  lsa[WPB], lsa2[WPB];
    lred[wv][lane] = make_float4(accre0, accre1, accim0, accim1);
    float ss = accsa, ss2 = accsa2;
    #pragma unroll
    for (int off = 32; off > 0; off >>= 1) { ss += __shfl_xor(ss, off); ss2 += __shfl_xor(ss2, off); }
    if (lane == 0) { lsa[wv] = ss; lsa2[wv] = ss2; }
    __syncthreads();
    if (tid < 64) {
        const float4 a = lred[0][tid], b = lred[1][tid], c = lred[2][tid], d = lred[3][tid];
        P[(2*tid  )*NBLK + blk]     = a.x + b.x + c.x + d.x;
        P[(2*tid+1)*NBLK + blk]     = a.y + b.y + c.y + d.y;
        P[(128+2*tid)*NBLK + blk]   = a.z + b.z + c.z + d.z;
        P[(129+2*tid)*NBLK + blk]   = a.w + b.w + c.w + d.w;
    }
    if (tid == 0) {
        p_sa [blk] = lsa[0]  + lsa[1]  + lsa[2]  + lsa[3];
        p_sa2[blk] = lsa2[0] + lsa2[1] + lsa2[2] + lsa2[3];
    }
}

// ---------------- reductions ----------------
__global__ void k_red(const float* __restrict__ P, float* __restrict__ mean)
{
    __shared__ double red[256];
    const int r = blockIdx.x, tid = threadIdx.x;
    double s = 0.0;
    #pragma unroll
    for (int k = 0; k < NBLK/256; ++k) s += (double)P[(size_t)r*NBLK + tid + 256*k];
    red[tid] = s;
    __syncthreads();
    for (int st = 128; st > 0; st >>= 1) { if (tid < st) red[tid] += red[tid + st]; __syncthreads(); }
    if (tid == 0) mean[r] = (float)(red[0] / (double)N_CELLS);
}

__global__ void k_final(const float* __restrict__ mean_in,
                        const float* __restrict__ p_sa, const float* __restrict__ p_sa2,
                        const float* __restrict__ W_dec, const float* __restrict__ b_dec,
                        float* __restrict__ out)
{
    __shared__ float  mean[2*HIDDEN];
    __shared__ double dred[256];
    __shared__ double tots[2];
    const int tid = threadIdx.x;
    mean[tid] = mean_in[tid];
    double sa = 0.0, sa2 = 0.0;
    #pragma unroll
    for (int k = 0; k < NBLK/256; ++k) {
        sa  += (double)p_sa [tid + 256*k];
        sa2 += (double)p_sa2[tid + 256*k];
    }
    dred[tid] = sa;
    __syncthreads();
    for (int s = 128; s > 0; s >>= 1) { if (tid < s) dred[tid] += dred[tid + s]; __syncthreads(); }
    if (tid == 0) tots[0] = dred[0];
    __syncthreads();
    dred[tid] = sa2;
    __syncthreads();
    for (int s = 128; s > 0; s >>= 1) { if (tid < s) dred[tid] += dred[tid + s]; __syncthreads(); }
    if (tid == 0) tots[1] = dred[0];
    __syncthreads();

    if (tid < IN_DIM) {
        float acc = b_dec[tid];
        #pragma unroll 8
        for (int c = 0; c < 2*HIDDEN; ++c) acc = fmaf(mean[c], W_dec[tid*2*HIDDEN + c], acc);
        out[tid] = acc;
    }
    if (tid == 0) {
        const double M = (double)N_CELLS * (double)HIDDEN;
        const double var = (tots[1] - tots[0]*tots[0]/M) / (M - 1.0);
        out[IN_DIM] = (float)var;
    }
}

extern "C" void kernel_launch(void* const* d_in, const int* in_sizes, int n_in,
                              void* d_out, int out_size, void* d_ws, size_t ws_size,
                              hipStream_t stream)
{
    const float* x       = (const float*)d_in[0];
    const float* amp     = (const float*)d_in[1];
    const float* phase   = (const float*)d_in[2];
    const float* vel     = (const float*)d_in[3];
    const int*   nbr_idx = (const int*)d_in[4];
    const float* nbr_sgn = (const float*)d_in[5];
    const void*  nbr_msk = d_in[6];
    const float* W_in    = (const float*)d_in[7];
    const float* b_in    = (const float*)d_in[8];
    const float* W_dec   = (const float*)d_in[9];
    const float* b_dec   = (const float*)d_in[10];
    const int*   step    = (const int*)d_in[11];

    char* wsb = (char*)d_ws;
    float* pp    = (float*)(wsb + WS_PP);
    int*   flag  = (int*)  (wsb + WS_FLAG);
    float* strg  = (float*)(wsb + WS_STR);
    float* P     = (float*)(wsb + WS_P);
    float* p_sa  = (float*)(wsb + WS_SA);
    float* p_sa2 = (float*)(wsb + WS_SA2);
    float* meanb = (float*)(wsb + WS_MEAN);
    float* out   = (float*)d_out;

    k_sp<<<N_CELLS/4 + 1, 256, 0, stream>>>(amp, strg, x, W_in, b_in,
                                            (const unsigned char*)nbr_msk, pp, flag);
    k_main2<<<NBLK, 256, 0, stream>>>(amp, phase, vel, nbr_idx, nbr_sgn, nbr_msk,
                                      step, pp, flag, strg, P, p_sa, p_sa2);
    k_red<<<256, 256, 0, stream>>>(P, meanb);
    k_final<<<1, 256, 0, stream>>>(meanb, p_sa, p_sa2, W_dec, b_dec, out);
}

// Round 5
// 70.406 us; speedup vs baseline: 3.1530x; 1.1212x over previous
//
#include <hip/hip_runtime.h>
#include <hip/hip_fp16.h>
#include <math.h>

#define N_CELLS 65536
#define HIDDEN  128
#define IN_DIM  64
#define MAX_DEG 6

#define WPB    4                    // waves per block (k_main)
#define NPB    32                   // nodes per block
#define NBLK   (N_CELLS/NPB)        // 2048 main-kernel blocks
#define CHUNK  4                    // iterations per wave (2 nodes per iter)

#define INV2PI 0.15915494309189535f

__device__ __forceinline__ void fsincos(float x, float& s, float& c) {
    const float r = x * INV2PI;                     // revolutions for v_sin/v_cos
    s = __builtin_amdgcn_sinf(r);
    c = __builtin_amdgcn_cosf(r);
}

// ---------------- ws offsets (~34.5 MB) ----------------
#define WS_PP    0                                  // 128 f32
#define WS_FLAG  512                                // 1 int
#define WS_STR   1024                               // 65536 f32
#define WS_S     (1024 + N_CELLS*4)                 // 65536 x 512B fp16 states (32 MB)
#define WS_P     (WS_S + (size_t)N_CELLS*512)       // 256 x NBLK f32 (2 MB)
#define WS_SA    (WS_P + 256*NBLK*4)                // NBLK f32
#define WS_SA2   (WS_SA + NBLK*4)                   // NBLK f32
#define WS_MEAN  (WS_SA2 + NBLK*4)                  // 256 f32

// k_pre: S[i][h] = (R,I) fp16 = amp*e^{i(phase+0.1vel)}; strength[i]=sum_h amp.
// Last block: prep (pp, mask-layout flag).
__global__ __launch_bounds__(256) void k_pre(
    const float* __restrict__ amp, const float* __restrict__ phase,
    const float* __restrict__ vel,
    const float* __restrict__ x, const float* __restrict__ W_in,
    const float* __restrict__ b_in, const unsigned char* __restrict__ maskb,
    int4* __restrict__ S, float* __restrict__ strength,
    float* __restrict__ pp, int* __restrict__ flag)
{
    const int tid = threadIdx.x;
    if (blockIdx.x < N_CELLS/8) {
        const int node = blockIdx.x*8 + (tid >> 5);
        const int hl   = tid & 31;
        const size_t ro = (size_t)node*HIDDEN + 4*hl;
        const float4 a = *(const float4*)(amp   + ro);
        const float4 p = *(const float4*)(phase + ro);
        const float4 v = *(const float4*)(vel   + ro);
        float s0,c0,s1,c1,s2,c2,s3,c3;
        fsincos(fmaf(0.1f, v.x, p.x), s0, c0);
        fsincos(fmaf(0.1f, v.y, p.y), s1, c1);
        fsincos(fmaf(0.1f, v.z, p.z), s2, c2);
        fsincos(fmaf(0.1f, v.w, p.w), s3, c3);
        union { int4 v4; __half2 h[4]; } u;
        u.h[0] = __floats2half2_rn(a.x*c0, a.x*s0);
        u.h[1] = __floats2half2_rn(a.y*c1, a.y*s1);
        u.h[2] = __floats2half2_rn(a.z*c2, a.z*s2);
        u.h[3] = __floats2half2_rn(a.w*c3, a.w*s3);
        S[(size_t)node*32 + hl] = u.v4;
        float st = a.x + a.y + a.z + a.w;
        #pragma unroll
        for (int off = 16; off > 0; off >>= 1) st += __shfl_xor(st, off);
        if (hl == 0) strength[node] = st;
        return;
    }
    __shared__ float sig[HIDDEN];
    __shared__ float red[HIDDEN];
    __shared__ int fl[256];
    if (tid < HIDDEN) {
        float acc = b_in[tid];
        #pragma unroll 8
        for (int d = 0; d < IN_DIM; ++d) acc = fmaf(W_in[tid*IN_DIM + d], x[d], acc);
        sig[tid] = acc;
        red[tid] = fabsf(acc);
    }
    int v = 0;
    #pragma unroll
    for (int r = 0; r < 4; ++r) v |= (int)maskb[(tid + 256*r)*4 + 1];
    fl[tid] = v;
    __syncthreads();
    for (int s = 64; s > 0; s >>= 1) {
        if (tid < s) red[tid] = fmaxf(red[tid], red[tid + s]);
        __syncthreads();
    }
    for (int s = 128; s > 0; s >>= 1) {
        if (tid < s) fl[tid] |= fl[tid + s];
        __syncthreads();
    }
    if (tid < HIDDEN) pp[tid] = sig[tid] / (red[0] + 1e-8f) * 0.314159265358979f;
    if (tid == 0) *flag = (fl[0] != 0) ? 1 : 0;   // 1 => 1-byte bool layout
}

// MAIN: 32 nodes/block; each wave handles 2 nodes per iteration (32 lanes each,
// lane owns 4 complex h). Compacted edge list; fp16 S gathers (16B per slot).
__global__ __launch_bounds__(256) void k_mainc(
    const int4* __restrict__ S, const int* __restrict__ nbr_idx,
    const float* __restrict__ nbr_sign, const void* __restrict__ nbr_mask,
    const int* __restrict__ step, const float* __restrict__ pp,
    const int* __restrict__ flagp, const float* __restrict__ strength,
    float* __restrict__ P, float* __restrict__ p_sa, float* __restrict__ p_sa2)
{
    __shared__ int   lji[NPB][MAX_DEG];
    __shared__ float lsk[NPB][MAX_DEG];
    __shared__ int   lwp[NPB][8];    // [0..5]=compacted words, [6]=deg, [7]=jb
    __shared__ float4 lredre[WPB][32], lredim[WPB][32];
    __shared__ float  lsa[WPB], lsa2[WPB];

    const int tid   = threadIdx.x;
    const int blk   = blockIdx.x;
    const int node0 = blk * NPB;

    // ---- prologue: parallel edge fetch, then per-node compaction + argmax ----
    if (tid < NPB*MAX_DEG) {
        const int flagv = *flagp;
        const unsigned char* mb = (const unsigned char*)nbr_mask;
        const int*           mi = (const int*)nbr_mask;
        const int n = tid / MAX_DEG, k = tid - n*MAX_DEG;
        const int e = (node0 + n)*MAX_DEG + k;
        const int m = flagv ? (mb[e] != 0) : (mi[e] != 0);
        const int j = nbr_idx[e];
        const float sg = nbr_sign[e];
        lji[n][k] = m ? (j | ((sg < 0.0f) ? (1<<24) : 0) | (1<<25)) : 0;
        lsk[n][k] = m ? strength[j] : -3.0e38f;
    }
    __syncthreads();
    if (tid < NPB) {
        int cnt = 0, jb = 0; float bv = -3.0e38f;
        #pragma unroll
        for (int k = 0; k < MAX_DEG; ++k) {
            const int w = lji[tid][k];
            if (w >> 25) lwp[tid][cnt++] = w;
            const float sv = lsk[tid][k];
            if (sv > bv) { bv = sv; jb = w & 0xFFFF; }   // strict > keeps first max
        }
        for (int k = cnt; k < MAX_DEG; ++k) lwp[tid][k] = 0;
        lwp[tid][6] = cnt;
        lwp[tid][7] = jb;
    }
    __syncthreads();

    const int wv   = tid >> 6;
    const int lane = tid & 63;
    const int half = lane >> 5;
    const int lh   = lane & 31;
    const float trev = 0.1f * (float)step[0] * INV2PI;
    const float4 ppv = ((const float4*)pp)[lh];     // pp[4lh..4lh+3]

    float accre[4] = {0,0,0,0}, accim[4] = {0,0,0,0};
    float accsa = 0.f, accsa2 = 0.f;

    for (int c = 0; c < CHUNK; ++c) {
        const int nl = wv*(2*CHUNK) + 2*c + half;
        const int i  = node0 + nl;
        const int4 A0 = *(const int4*)&lwp[nl][0];
        const int4 A1 = *(const int4*)&lwp[nl][4];
        const int deg = A1.z, jb = A1.w;
        const int kmax = max(deg, __shfl_xor(deg, 32));  // wave-uniform

        // self state (4 complex)
        union { int4 v4; __half2 h[4]; } us;
        us.v4 = S[(size_t)i*32 + lh];
        float R[4], I[4], inva[4];
        #pragma unroll
        for (int q = 0; q < 4; ++q) {
            const float2 e = __half22float2(us.h[q]);
            R[q] = e.x; I[q] = e.y;
            inva[q] = __builtin_amdgcn_rsqf(e.x*e.x + e.y*e.y);
        }

        // ---- compacted neighbor interference ----
        float ir[4] = {0,0,0,0}, ii[4] = {0,0,0,0};
        const int slots[MAX_DEG] = {A0.x, A0.y, A0.z, A0.w, A1.x, A1.y};
        #pragma unroll
        for (int k = 0; k < MAX_DEG; ++k) {
            if (k >= kmax) break;
            const int w = slots[k];
            const unsigned j = (unsigned)(w & 0xFFFF);
            const float sgnm = (w & (1<<25)) ? ((w & (1<<24)) ? -1.0f : 1.0f) : 0.0f;
            union { int4 v4; __half2 h[4]; } uj;
            uj.v4 = S[(size_t)j*32 + lh];
            #pragma unroll
            for (int q = 0; q < 4; ++q) {
                const float2 e = __half22float2(uj.h[q]);
                const float E = R[q]*e.x + I[q]*e.y;         // a_i a_j cosD
                const float g = sgnm * E * __builtin_amdgcn_rsqf(e.x*e.x + e.y*e.y);
                ir[q] = fmaf(g, e.x, ir[q]);
                ii[q] = fmaf(g, e.y, ii[q]);
            }
        }

        // new = 0.7*state + (0.3*0.1/deg)*interference/a_i  (deg >= 1 always)
        const float f = 0.03f * __builtin_amdgcn_rcpf((float)deg);
        float nr[4], ni[4];
        #pragma unroll
        for (int q = 0; q < 4; ++q) {
            const float fq = f * inva[q];
            nr[q] = fmaf(0.7f, R[q], fq*ir[q]);
            ni[q] = fmaf(0.7f, I[q], fq*ii[q]);
        }

        // ---- morphism: new += 0.02 * new*conj(src)/|new| ----
        if (deg >= 2) {
            union { int4 v4; __half2 h[4]; } ub;
            ub.v4 = S[(size_t)jb*32 + lh];
            #pragma unroll
            for (int q = 0; q < 4; ++q) {
                const float2 e = __half22float2(ub.h[q]);
                const float im = 0.02f * __builtin_amdgcn_rsqf(nr[q]*nr[q] + ni[q]*ni[q]);
                const float mr = im*(nr[q]*e.x + ni[q]*e.y);
                const float mi = im*(ni[q]*e.x - nr[q]*e.y);
                nr[q] += mr; ni[q] += mi;
            }
        }

        // ---- traveling wave ----
        const float wr = fmaf((float)i, 1.52587890625e-5f, trev);
        const float wf = 1.0f + 0.02f * __builtin_amdgcn_sinf(wr);
        #pragma unroll
        for (int q = 0; q < 4; ++q) { nr[q] *= wf; ni[q] *= wf; }

        // ---- input-driven phase rotation for i < 32 ----
        if (i < 32) {
            const float fac = 0.1f / fmaf(0.1f, (float)i, 1.0f);
            const float pv[4] = {ppv.x, ppv.y, ppv.z, ppv.w};
            #pragma unroll
            for (int q = 0; q < 4; ++q) {
                float sp, cp;
                fsincos(pv[q]*fac, sp, cp);
                const float tr = nr[q]*cp - ni[q]*sp;
                ni[q] = ni[q]*cp + nr[q]*sp;
                nr[q] = tr;
            }
        }

        // ---- amplitude renorm: cs = new/(rowmax|new|+1e-8) ----
        float m[4];
        #pragma unroll
        for (int q = 0; q < 4; ++q) m[q] = sqrtf(nr[q]*nr[q] + ni[q]*ni[q]);
        float lm = fmaxf(fmaxf(m[0], m[1]), fmaxf(m[2], m[3]));
        #pragma unroll
        for (int off = 16; off > 0; off >>= 1) lm = fmaxf(lm, __shfl_xor(lm, off));
        const float sc = 1.0f / (lm + 1e-8f);
        #pragma unroll
        for (int q = 0; q < 4; ++q) {
            accre[q] += nr[q]*sc;
            accim[q] += ni[q]*sc;
            const float A = m[q]*sc;
            accsa  += A;
            accsa2 += A*A;
        }
    }

    // ---- cross-half then cross-wave reduction ----
    #pragma unroll
    for (int q = 0; q < 4; ++q) {
        accre[q] += __shfl_xor(accre[q], 32);
        accim[q] += __shfl_xor(accim[q], 32);
    }
    #pragma unroll
    for (int off = 32; off > 0; off >>= 1) {
        accsa  += __shfl_xor(accsa,  off);
        accsa2 += __shfl_xor(accsa2, off);
    }
    if (half == 0) {
        lredre[wv][lh] = make_float4(accre[0], accre[1], accre[2], accre[3]);
        lredim[wv][lh] = make_float4(accim[0], accim[1], accim[2], accim[3]);
    }
    if (lane == 0) { lsa[wv] = accsa; lsa2[wv] = accsa2; }
    __syncthreads();
    if (tid < 32) {
        float4 r = lredre[0][tid], im = lredim[0][tid];
        #pragma unroll
        for (int w = 1; w < WPB; ++w) {
            const float4 a = lredre[w][tid], b = lredim[w][tid];
            r.x += a.x; r.y += a.y; r.z += a.z; r.w += a.w;
            im.x += b.x; im.y += b.y; im.z += b.z; im.w += b.w;
        }
        P[(4*tid  )*NBLK + blk]       = r.x;
        P[(4*tid+1)*NBLK + blk]       = r.y;
        P[(4*tid+2)*NBLK + blk]       = r.z;
        P[(4*tid+3)*NBLK + blk]       = r.w;
        P[(128+4*tid  )*NBLK + blk]   = im.x;
        P[(128+4*tid+1)*NBLK + blk]   = im.y;
        P[(128+4*tid+2)*NBLK + blk]   = im.z;
        P[(128+4*tid+3)*NBLK + blk]   = im.w;
    }
    if (tid == 0) {
        p_sa [blk] = lsa[0]  + lsa[1]  + lsa[2]  + lsa[3];
        p_sa2[blk] = lsa2[0] + lsa2[1] + lsa2[2] + lsa2[3];
    }
}

// ---------------- reductions ----------------
__global__ void k_red(const float* __restrict__ P, float* __restrict__ mean)
{
    __shared__ double red[256];
    const int r = blockIdx.x, tid = threadIdx.x;
    double s = 0.0;
    #pragma unroll
    for (int k = 0; k < NBLK/256; ++k) s += (double)P[(size_t)r*NBLK + tid + 256*k];
    red[tid] = s;
    __syncthreads();
    for (int st = 128; st > 0; st >>= 1) { if (tid < st) red[tid] += red[tid + st]; __syncthreads(); }
    if (tid == 0) mean[r] = (float)(red[0] / (double)N_CELLS);
}

__global__ void k_final(const float* __restrict__ mean_in,
                        const float* __restrict__ p_sa, const float* __restrict__ p_sa2,
                        const float* __restrict__ W_dec, const float* __restrict__ b_dec,
                        float* __restrict__ out)
{
    __shared__ float  mean[2*HIDDEN];
    __shared__ double dred[256];
    __shared__ double tots[2];
    const int tid = threadIdx.x;
    mean[tid] = mean_in[tid];
    double sa = 0.0, sa2 = 0.0;
    #pragma unroll
    for (int k = 0; k < NBLK/256; ++k) {
        sa  += (double)p_sa [tid + 256*k];
        sa2 += (double)p_sa2[tid + 256*k];
    }
    dred[tid] = sa;
    __syncthreads();
    for (int s = 128; s > 0; s >>= 1) { if (tid < s) dred[tid] += dred[tid + s]; __syncthreads(); }
    if (tid == 0) tots[0] = dred[0];
    __syncthreads();
    dred[tid] = sa2;
    __syncthreads();
    for (int s = 128; s > 0; s >>= 1) { if (tid < s) dred[tid] += dred[tid + s]; __syncthreads(); }
    if (tid == 0) tots[1] = dred[0];
    __syncthreads();

    if (tid < IN_DIM) {
        float acc = b_dec[tid];
        #pragma unroll 8
        for (int c = 0; c < 2*HIDDEN; ++c) acc = fmaf(mean[c], W_dec[tid*2*HIDDEN + c], acc);
        out[tid] = acc;
    }
    if (tid == 0) {
        const double M = (double)N_CELLS * (double)HIDDEN;
        const double var = (tots[1] - tots[0]*tots[0]/M) / (M - 1.0);
        out[IN_DIM] = (float)var;
    }
}

extern "C" void kernel_launch(void* const* d_in, const int* in_sizes, int n_in,
                              void* d_out, int out_size, void* d_ws, size_t ws_size,
                              hipStream_t stream)
{
    const float* x       = (const float*)d_in[0];
    const float* amp     = (const float*)d_in[1];
    const float* phase   = (const float*)d_in[2];
    const float* vel     = (const float*)d_in[3];
    const int*   nbr_idx = (const int*)d_in[4];
    const float* nbr_sgn = (const float*)d_in[5];
    const void*  nbr_msk = d_in[6];
    const float* W_in    = (const float*)d_in[7];
    const float* b_in    = (const float*)d_in[8];
    const float* W_dec   = (const float*)d_in[9];
    const float* b_dec   = (const float*)d_in[10];
    const int*   step    = (const int*)d_in[11];

    char* wsb = (char*)d_ws;
    float* pp    = (float*)(wsb + WS_PP);
    int*   flag  = (int*)  (wsb + WS_FLAG);
    float* strg  = (float*)(wsb + WS_STR);
    int4*  S     = (int4*) (wsb + WS_S);
    float* P     = (float*)(wsb + WS_P);
    float* p_sa  = (float*)(wsb + WS_SA);
    float* p_sa2 = (float*)(wsb + WS_SA2);
    float* meanb = (float*)(wsb + WS_MEAN);
    float* out   = (float*)d_out;

    k_pre<<<N_CELLS/8 + 1, 256, 0, stream>>>(amp, phase, vel, x, W_in, b_in,
                                             (const unsigned char*)nbr_msk,
                                             S, strg, pp, flag);
    k_mainc<<<NBLK, 256, 0, stream>>>(S, nbr_idx, nbr_sgn, nbr_msk,
                                      step, pp, flag, strg, P, p_sa, p_sa2);
    k_red<<<256, 256, 0, stream>>>(P, meanb);
    k_final<<<1, 256, 0, stream>>>(meanb, p_sa, p_sa2, W_dec, b_dec, out);
}

// Round 6
// 67.769 us; speedup vs baseline: 3.2756x; 1.0389x over previous
//
#include <hip/hip_runtime.h>
#include <hip/hip_fp16.h>
#include <math.h>

#define N_CELLS 65536
#define HIDDEN  128
#define IN_DIM  64
#define MAX_DEG 6

#define WPB    4                    // waves per block (k_main)
#define NPB    32                   // nodes per block
#define NBLK   (N_CELLS/NPB)        // 2048 main-kernel blocks
#define CHUNK  4                    // iterations per wave (2 nodes per iter)

#define INV2PI 0.15915494309189535f

__device__ __forceinline__ void fsincos(float x, float& s, float& c) {
    const float r = x * INV2PI;                     // revolutions for v_sin/v_cos
    s = __builtin_amdgcn_sinf(r);
    c = __builtin_amdgcn_cosf(r);
}

// ---------------- ws offsets (~34.5 MB) ----------------
#define WS_PP    0                                  // 128 f32
#define WS_FLAG  512                                // 1 int
#define WS_STR   1024                               // 65536 f32
#define WS_S     (1024 + N_CELLS*4)                 // 65536 x 512B fp16 states (32 MB)
#define WS_P     (WS_S + (size_t)N_CELLS*512)       // 256 x NBLK f32 (2 MB)
#define WS_SA    (WS_P + 256*NBLK*4)                // NBLK f32
#define WS_SA2   (WS_SA + NBLK*4)                   // NBLK f32
#define WS_MEAN  (WS_SA2 + NBLK*4)                  // 256 f32

// k_pre: S[i][h] = (R,I) fp16 = amp*e^{i(phase+0.1vel)}; strength[i]=sum_h amp.
// Last block: prep (pp, mask-layout flag).
__global__ __launch_bounds__(256) void k_pre(
    const float* __restrict__ amp, const float* __restrict__ phase,
    const float* __restrict__ vel,
    const float* __restrict__ x, const float* __restrict__ W_in,
    const float* __restrict__ b_in, const unsigned char* __restrict__ maskb,
    int4* __restrict__ S, float* __restrict__ strength,
    float* __restrict__ pp, int* __restrict__ flag)
{
    const int tid = threadIdx.x;
    if (blockIdx.x < N_CELLS/8) {
        const int node = blockIdx.x*8 + (tid >> 5);
        const int hl   = tid & 31;
        const size_t ro = (size_t)node*HIDDEN + 4*hl;
        const float4 a = *(const float4*)(amp   + ro);
        const float4 p = *(const float4*)(phase + ro);
        const float4 v = *(const float4*)(vel   + ro);
        float s0,c0,s1,c1,s2,c2,s3,c3;
        fsincos(fmaf(0.1f, v.x, p.x), s0, c0);
        fsincos(fmaf(0.1f, v.y, p.y), s1, c1);
        fsincos(fmaf(0.1f, v.z, p.z), s2, c2);
        fsincos(fmaf(0.1f, v.w, p.w), s3, c3);
        union { int4 v4; __half2 h[4]; } u;
        u.h[0] = __floats2half2_rn(a.x*c0, a.x*s0);
        u.h[1] = __floats2half2_rn(a.y*c1, a.y*s1);
        u.h[2] = __floats2half2_rn(a.z*c2, a.z*s2);
        u.h[3] = __floats2half2_rn(a.w*c3, a.w*s3);
        S[(size_t)node*32 + hl] = u.v4;
        float st = a.x + a.y + a.z + a.w;
        #pragma unroll
        for (int off = 16; off > 0; off >>= 1) st += __shfl_xor(st, off);
        if (hl == 0) strength[node] = st;
        return;
    }
    __shared__ float sig[HIDDEN];
    __shared__ float red[HIDDEN];
    __shared__ int fl[256];
    if (tid < HIDDEN) {
        float acc = b_in[tid];
        #pragma unroll 8
        for (int d = 0; d < IN_DIM; ++d) acc = fmaf(W_in[tid*IN_DIM + d], x[d], acc);
        sig[tid] = acc;
        red[tid] = fabsf(acc);
    }
    int v = 0;
    #pragma unroll
    for (int r = 0; r < 4; ++r) v |= (int)maskb[(tid + 256*r)*4 + 1];
    fl[tid] = v;
    __syncthreads();
    for (int s = 64; s > 0; s >>= 1) {
        if (tid < s) red[tid] = fmaxf(red[tid], red[tid + s]);
        __syncthreads();
    }
    for (int s = 128; s > 0; s >>= 1) {
        if (tid < s) fl[tid] |= fl[tid + s];
        __syncthreads();
    }
    if (tid < HIDDEN) pp[tid] = sig[tid] / (red[0] + 1e-8f) * 0.314159265358979f;
    if (tid == 0) *flag = (fl[0] != 0) ? 1 : 0;   // 1 => 1-byte bool layout
}

// MAIN: 32 nodes/block; each wave handles 2 nodes per iteration (32 lanes each,
// lane owns 4 complex h). Compacted edges; PREFETCH-then-compute (all gathers
// issued back-to-back into registers before any arithmetic uses them).
__global__ __launch_bounds__(256) void k_mainc(
    const int4* __restrict__ S, const int* __restrict__ nbr_idx,
    const float* __restrict__ nbr_sign, const void* __restrict__ nbr_mask,
    const int* __restrict__ step, const float* __restrict__ pp,
    const int* __restrict__ flagp, const float* __restrict__ strength,
    float* __restrict__ P, float* __restrict__ p_sa, float* __restrict__ p_sa2)
{
    __shared__ int   lji[NPB][MAX_DEG];
    __shared__ float lsk[NPB][MAX_DEG];
    __shared__ int   lwp[NPB][8];    // [0..5]=compacted words, [6]=deg, [7]=jb
    __shared__ float4 lredre[WPB][32], lredim[WPB][32];
    __shared__ float  lsa[WPB], lsa2[WPB];

    const int tid   = threadIdx.x;
    const int blk   = blockIdx.x;
    const int node0 = blk * NPB;

    // ---- prologue: parallel edge fetch, then per-node compaction + argmax ----
    if (tid < NPB*MAX_DEG) {
        const int flagv = *flagp;
        const unsigned char* mb = (const unsigned char*)nbr_mask;
        const int*           mi = (const int*)nbr_mask;
        const int n = tid / MAX_DEG, k = tid - n*MAX_DEG;
        const int e = (node0 + n)*MAX_DEG + k;
        const int m = flagv ? (mb[e] != 0) : (mi[e] != 0);
        const int j = nbr_idx[e];
        const float sg = nbr_sign[e];
        lji[n][k] = m ? (j | ((sg < 0.0f) ? (1<<24) : 0) | (1<<25)) : 0;
        lsk[n][k] = m ? strength[j] : -3.0e38f;
    }
    __syncthreads();
    if (tid < NPB) {
        int cnt = 0, jb = 0; float bv = -3.0e38f;
        #pragma unroll
        for (int k = 0; k < MAX_DEG; ++k) {
            const int w = lji[tid][k];
            if (w >> 25) lwp[tid][cnt++] = w;
            const float sv = lsk[tid][k];
            if (sv > bv) { bv = sv; jb = w & 0xFFFF; }   // strict > keeps first max
        }
        for (int k = cnt; k < MAX_DEG; ++k) lwp[tid][k] = 0;
        lwp[tid][6] = cnt;
        lwp[tid][7] = jb;
    }
    __syncthreads();

    const int wv   = tid >> 6;
    const int lane = tid & 63;
    const int half = lane >> 5;
    const int lh   = lane & 31;
    const float trev = 0.1f * (float)step[0] * INV2PI;
    const float4 ppv = ((const float4*)pp)[lh];     // pp[4lh..4lh+3]

    float accre[4] = {0,0,0,0}, accim[4] = {0,0,0,0};
    float accsa = 0.f, accsa2 = 0.f;

    #pragma unroll 1
    for (int c = 0; c < CHUNK; ++c) {
        const int nl = wv*(2*CHUNK) + 2*c + half;
        const int i  = node0 + nl;
        const int4 A0 = *(const int4*)&lwp[nl][0];
        const int4 A1 = *(const int4*)&lwp[nl][4];
        const int deg = A1.z, jb = A1.w;
        const int kmax = max(deg, __shfl_xor(deg, 32));  // wave-uniform

        const int slots[MAX_DEG] = {A0.x, A0.y, A0.z, A0.w, A1.x, A1.y};

        // ---- PREFETCH phase: self + best + kmax neighbors, all in flight ----
        union H { int4 v4; __half2 h[4]; };
        H us, ub, nb[MAX_DEG];
        us.v4 = S[(size_t)(unsigned)i *32 + lh];
        ub.v4 = S[(size_t)(unsigned)jb*32 + lh];    // jb always a valid node
        #pragma unroll
        for (int k = 0; k < MAX_DEG; ++k)
            if (k < kmax) nb[k].v4 = S[(size_t)(unsigned)(slots[k] & 0xFFFF)*32 + lh];

        // ---- COMPUTE phase ----
        float R[4], I[4], inva[4];
        #pragma unroll
        for (int q = 0; q < 4; ++q) {
            const float2 e = __half22float2(us.h[q]);
            R[q] = e.x; I[q] = e.y;
            inva[q] = __builtin_amdgcn_rsqf(e.x*e.x + e.y*e.y);
        }

        float ir[4] = {0,0,0,0}, ii[4] = {0,0,0,0};
        #pragma unroll
        for (int k = 0; k < MAX_DEG; ++k) {
            if (k < kmax) {
                const int w = slots[k];
                const float sgnm = (w & (1<<25)) ? ((w & (1<<24)) ? -1.0f : 1.0f) : 0.0f;
                #pragma unroll
                for (int q = 0; q < 4; ++q) {
                    const float2 e = __half22float2(nb[k].h[q]);
                    const float E = R[q]*e.x + I[q]*e.y;         // a_i a_j cosD
                    const float g = sgnm * E * __builtin_amdgcn_rsqf(e.x*e.x + e.y*e.y);
                    ir[q] = fmaf(g, e.x, ir[q]);
                    ii[q] = fmaf(g, e.y, ii[q]);
                }
            }
        }

        // new = 0.7*state + (0.3*0.1/deg)*interference/a_i  (deg >= 1 always)
        const float f = 0.03f * __builtin_amdgcn_rcpf((float)deg);
        float nr[4], ni[4];
        #pragma unroll
        for (int q = 0; q < 4; ++q) {
            const float fq = f * inva[q];
            nr[q] = fmaf(0.7f, R[q], fq*ir[q]);
            ni[q] = fmaf(0.7f, I[q], fq*ii[q]);
        }

        // ---- morphism: new += 0.02 * new*conj(src)/|new| ----
        if (deg >= 2) {
            #pragma unroll
            for (int q = 0; q < 4; ++q) {
                const float2 e = __half22float2(ub.h[q]);
                const float im = 0.02f * __builtin_amdgcn_rsqf(nr[q]*nr[q] + ni[q]*ni[q]);
                const float mr = im*(nr[q]*e.x + ni[q]*e.y);
                const float mi = im*(ni[q]*e.x - nr[q]*e.y);
                nr[q] += mr; ni[q] += mi;
            }
        }

        // ---- traveling wave ----
        const float wr = fmaf((float)i, 1.52587890625e-5f, trev);
        const float wf = 1.0f + 0.02f * __builtin_amdgcn_sinf(wr);
        #pragma unroll
        for (int q = 0; q < 4; ++q) { nr[q] *= wf; ni[q] *= wf; }

        // ---- input-driven phase rotation for i < 32 ----
        if (i < 32) {
            const float fac = 0.1f / fmaf(0.1f, (float)i, 1.0f);
            const float pv[4] = {ppv.x, ppv.y, ppv.z, ppv.w};
            #pragma unroll
            for (int q = 0; q < 4; ++q) {
                float sp, cp;
                fsincos(pv[q]*fac, sp, cp);
                const float tr = nr[q]*cp - ni[q]*sp;
                ni[q] = ni[q]*cp + nr[q]*sp;
                nr[q] = tr;
            }
        }

        // ---- amplitude renorm: cs = new/(rowmax|new|+1e-8) ----
        float m[4];
        #pragma unroll
        for (int q = 0; q < 4; ++q) m[q] = sqrtf(nr[q]*nr[q] + ni[q]*ni[q]);
        float lm = fmaxf(fmaxf(m[0], m[1]), fmaxf(m[2], m[3]));
        #pragma unroll
        for (int off = 16; off > 0; off >>= 1) lm = fmaxf(lm, __shfl_xor(lm, off));
        const float sc = 1.0f / (lm + 1e-8f);
        #pragma unroll
        for (int q = 0; q < 4; ++q) {
            accre[q] += nr[q]*sc;
            accim[q] += ni[q]*sc;
            const float A = m[q]*sc;
            accsa  += A;
            accsa2 += A*A;
        }
    }

    // ---- cross-half then cross-wave reduction ----
    #pragma unroll
    for (int q = 0; q < 4; ++q) {
        accre[q] += __shfl_xor(accre[q], 32);
        accim[q] += __shfl_xor(accim[q], 32);
    }
    #pragma unroll
    for (int off = 32; off > 0; off >>= 1) {
        accsa  += __shfl_xor(accsa,  off);
        accsa2 += __shfl_xor(accsa2, off);
    }
    if (half == 0) {
        lredre[wv][lh] = make_float4(accre[0], accre[1], accre[2], accre[3]);
        lredim[wv][lh] = make_float4(accim[0], accim[1], accim[2], accim[3]);
    }
    if (lane == 0) { lsa[wv] = accsa; lsa2[wv] = accsa2; }
    __syncthreads();
    if (tid < 32) {
        float4 r = lredre[0][tid], im = lredim[0][tid];
        #pragma unroll
        for (int w = 1; w < WPB; ++w) {
            const float4 a = lredre[w][tid], b = lredim[w][tid];
            r.x += a.x; r.y += a.y; r.z += a.z; r.w += a.w;
            im.x += b.x; im.y += b.y; im.z += b.z; im.w += b.w;
        }
        P[(4*tid  )*NBLK + blk]       = r.x;
        P[(4*tid+1)*NBLK + blk]       = r.y;
        P[(4*tid+2)*NBLK + blk]       = r.z;
        P[(4*tid+3)*NBLK + blk]       = r.w;
        P[(128+4*tid  )*NBLK + blk]   = im.x;
        P[(128+4*tid+1)*NBLK + blk]   = im.y;
        P[(128+4*tid+2)*NBLK + blk]   = im.z;
        P[(128+4*tid+3)*NBLK + blk]   = im.w;
    }
    if (tid == 0) {
        p_sa [blk] = lsa[0]  + lsa[1]  + lsa[2]  + lsa[3];
        p_sa2[blk] = lsa2[0] + lsa2[1] + lsa2[2] + lsa2[3];
    }
}

// ---------------- reductions ----------------
__global__ void k_red(const float* __restrict__ P, float* __restrict__ mean)
{
    __shared__ double red[256];
    const int r = blockIdx.x, tid = threadIdx.x;
    double s = 0.0;
    #pragma unroll
    for (int k = 0; k < NBLK/256; ++k) s += (double)P[(size_t)r*NBLK + tid + 256*k];
    red[tid] = s;
    __syncthreads();
    for (int st = 128; st > 0; st >>= 1) { if (tid < st) red[tid] += red[tid + st]; __syncthreads(); }
    if (tid == 0) mean[r] = (float)(red[0] / (double)N_CELLS);
}

__global__ void k_final(const float* __restrict__ mean_in,
                        const float* __restrict__ p_sa, const float* __restrict__ p_sa2,
                        const float* __restrict__ W_dec, const float* __restrict__ b_dec,
                        float* __restrict__ out)
{
    __shared__ float  mean[2*HIDDEN];
    __shared__ double dred[256];
    __shared__ double tots[2];
    const int tid = threadIdx.x;
    mean[tid] = mean_in[tid];
    double sa = 0.0, sa2 = 0.0;
    #pragma unroll
    for (int k = 0; k < NBLK/256; ++k) {
        sa  += (double)p_sa [tid + 256*k];
        sa2 += (double)p_sa2[tid + 256*k];
    }
    dred[tid] = sa;
    __syncthreads();
    for (int s = 128; s > 0; s >>= 1) { if (tid < s) dred[tid] += dred[tid + s]; __syncthreads(); }
    if (tid == 0) tots[0] = dred[0];
    __syncthreads();
    dred[tid] = sa2;
    __syncthreads();
    for (int s = 128; s > 0; s >>= 1) { if (tid < s) dred[tid] += dred[tid + s]; __syncthreads(); }
    if (tid == 0) tots[1] = dred[0];
    __syncthreads();

    if (tid < IN_DIM) {
        float acc = b_dec[tid];
        #pragma unroll 8
        for (int c = 0; c < 2*HIDDEN; ++c) acc = fmaf(mean[c], W_dec[tid*2*HIDDEN + c], acc);
        out[tid] = acc;
    }
    if (tid == 0) {
        const double M = (double)N_CELLS * (double)HIDDEN;
        const double var = (tots[1] - tots[0]*tots[0]/M) / (M - 1.0);
        out[IN_DIM] = (float)var;
    }
}

extern "C" void kernel_launch(void* const* d_in, const int* in_sizes, int n_in,
                              void* d_out, int out_size, void* d_ws, size_t ws_size,
                              hipStream_t stream)
{
    const float* x       = (const float*)d_in[0];
    const float* amp     = (const float*)d_in[1];
    const float* phase   = (const float*)d_in[2];
    const float* vel     = (const float*)d_in[3];
    const int*   nbr_idx = (const int*)d_in[4];
    const float* nbr_sgn = (const float*)d_in[5];
    const void*  nbr_msk = d_in[6];
    const float* W_in    = (const float*)d_in[7];
    const float* b_in    = (const float*)d_in[8];
    const float* W_dec   = (const float*)d_in[9];
    const float* b_dec   = (const float*)d_in[10];
    const int*   step    = (const int*)d_in[11];

    char* wsb = (char*)d_ws;
    float* pp    = (float*)(wsb + WS_PP);
    int*   flag  = (int*)  (wsb + WS_FLAG);
    float* strg  = (float*)(wsb + WS_STR);
    int4*  S     = (int4*) (wsb + WS_S);
    float* P     = (float*)(wsb + WS_P);
    float* p_sa  = (float*)(wsb + WS_SA);
    float* p_sa2 = (float*)(wsb + WS_SA2);
    float* meanb = (float*)(wsb + WS_MEAN);
    float* out   = (float*)d_out;

    k_pre<<<N_CELLS/8 + 1, 256, 0, stream>>>(amp, phase, vel, x, W_in, b_in,
                                             (const unsigned char*)nbr_msk,
                                             S, strg, pp, flag);
    k_mainc<<<NBLK, 256, 0, stream>>>(S, nbr_idx, nbr_sgn, nbr_msk,
                                      step, pp, flag, strg, P, p_sa, p_sa2);
    k_red<<<256, 256, 0, stream>>>(P, meanb);
    k_final<<<1, 256, 0, stream>>>(meanb, p_sa, p_sa2, W_dec, b_dec, out);
}